// Round 2
// baseline (9305.500 us; speedup 1.0000x reference)
//
#include <hip/hip_runtime.h>
#include <cstdint>
#include <cstddef>

// ---------------- ws layout (float elements) ----------------
// w1t: [16][64][9][64]  (e, ic, tap, oc)   589824 floats
// w2t: same                                589824 floats
// xp : [16][64]                            1024 floats
// gates: [16][16]                          256 floats
#define W1T_OFF   0
#define W2T_OFF   589824
#define XP_OFF    (589824*2)
#define GATES_OFF (XP_OFF + 1024)

__device__ __forceinline__ float bf2f(unsigned short h){
  return __uint_as_float(((uint32_t)h)<<16);
}
__device__ __forceinline__ unsigned short f2bf(float f){
  uint32_t u = __float_as_uint(f);
  u = u + 0x7fffu + ((u>>16)&1u);   // RNE
  return (unsigned short)(u>>16);
}
__device__ __forceinline__ float gelu_exact(float x){
  return 0.5f*x*(1.0f + erff(x*0.70710678118654752440f));
}

// ---------------- weight transpose: W[e][oc][ic][3][3] -> wT[e][ic][tap][oc]
__global__ __launch_bounds__(256) void wtrans_kernel(const float* __restrict__ W1,
                                                     const float* __restrict__ W2,
                                                     float* __restrict__ ws){
  int idx = blockIdx.x*256 + threadIdx.x;      // 0 .. 1,179,647
  const int N = 589824;
  int which = (idx >= N) ? 1 : 0;
  int i = idx - which*N;
  int oc = i & 63;
  int t  = (i>>6) % 9;
  int ic = (i/576) & 63;
  int e  = i/36864;
  const float* src = which ? W2 : W1;
  float v = src[(((e*64 + oc)*64 + ic)*9) + t];
  ws[(which ? W2T_OFF : W1T_OFF) + i] = v;
}

// ---------------- mean pool: xp[b][c] = mean_{h,w} x[b][c][h][w]
__global__ __launch_bounds__(256) void pool_kernel(const float* __restrict__ x,
                                                   float* __restrict__ ws){
  int bc = blockIdx.x;                        // 0..1023
  const float* p = x + (size_t)bc*16384;
  int tid = threadIdx.x;
  float s = 0.f;
  for (int i = tid; i < 16384; i += 256) s += p[i];
  for (int off = 32; off; off >>= 1) s += __shfl_down(s, off);
  __shared__ float r[4];
  if ((tid & 63) == 0) r[tid>>6] = s;
  __syncthreads();
  if (tid == 0) ws[XP_OFF + bc] = (r[0]+r[1]+r[2]+r[3]) * (1.0f/16384.0f);
}

// ---------------- gating: logits -> softmax -> top2 -> gates + aux
__global__ __launch_bounds__(256) void gate_kernel(const float* __restrict__ tf,
    const float* __restrict__ Wx, const float* __restrict__ Wt,
    const float* __restrict__ bg, float* __restrict__ ws,
    float* __restrict__ out_aux){
  __shared__ float lg[16][16];
  __shared__ float gsh[16][16];
  int tid = threadIdx.x;
  int b = tid >> 4, e = tid & 15;
  const float* xp = ws + XP_OFF;
  float acc = bg[e];
  for (int c = 0; c < 64;  ++c) acc += xp[b*64 + c] * Wx[c*16 + e];
  for (int d = 0; d < 512; ++d) acc += tf[b*512 + d] * Wt[d*16 + e];
  lg[b][e] = acc;
  __syncthreads();
  if (tid < 16) {
    int bb = tid;
    float m = -1e30f;
    for (int j = 0; j < 16; ++j) m = fmaxf(m, lg[bb][j]);
    float pr[16]; float s = 0.f;
    for (int j = 0; j < 16; ++j){ pr[j] = expf(lg[bb][j] - m); s += pr[j]; }
    float invs = 1.f/s;
    for (int j = 0; j < 16; ++j) pr[j] *= invs;
    int i1 = 0; float v1 = pr[0];
    for (int j = 1; j < 16; ++j) if (pr[j] > v1){ v1 = pr[j]; i1 = j; }
    float v2 = -1.f; int i2 = 0;
    for (int j = 0; j < 16; ++j) if (j != i1 && pr[j] > v2){ v2 = pr[j]; i2 = j; }
    float inv = 1.f/(v1 + v2);
    for (int j = 0; j < 16; ++j) gsh[bb][j] = 0.f;
    gsh[bb][i1] = v1*inv;
    gsh[bb][i2] = v2*inv;
    for (int j = 0; j < 16; ++j) ws[GATES_OFF + bb*16 + j] = gsh[bb][j];
  }
  __syncthreads();
  if (tid == 0){
    float imp[16]; float mean = 0.f;
    for (int j = 0; j < 16; ++j){
      float t = 0.f;
      for (int bb = 0; bb < 16; ++bb) t += gsh[bb][j];
      imp[j] = t; mean += t;
    }
    mean *= (1.f/16.f);
    float m2 = 0.f;
    for (int j = 0; j < 16; ++j){ float d = imp[j] - mean; m2 += d*d; }
    float var = m2 * (1.f/16.f);
    out_aux[0] = var / (mean*mean + 1e-10f);
  }
}

// ---------------- fused expert: conv3x3 -> GELU -> conv3x3 (+resample), gated accumulate
// TYPE 0: full res (S=128). TYPE 1: up2 -> block(S=256) -> maxpool2.
// TYPE 2: maxpool2 -> block(S=64) -> up2.
template<int TYPE>
__global__ __launch_bounds__(256) void expert_kernel(
    const float* __restrict__ x, const float* __restrict__ ws,
    const float* __restrict__ b1, const float* __restrict__ b2,
    float* __restrict__ out, int e)
{
  constexpr int S = (TYPE==0) ? 128 : ((TYPE==1) ? 256 : 64);
  constexpr int TILES = S/16;
  const int b = blockIdx.y;
  const float g = ws[GATES_OFF + b*16 + e];
  if (g == 0.0f) return;                       // inactive expert for this sample
  const int ty0 = (blockIdx.x / TILES)*16;
  const int tx0 = (blockIdx.x % TILES)*16;
  const int tid = threadIdx.x;

  __shared__ unsigned short h1[64][324];       // [oc][18*18] bf16, post-GELU

  const float* w1t  = ws + W1T_OFF + e*36864;  // [ic][tap][oc]
  const float* w2t  = ws + W2T_OFF + e*36864;
  const float* bias1 = b1 + e*64;
  const float* bias2 = b2 + e*64;
  const float* xb = x + (size_t)b*64*16384;

  // ---- conv1 + GELU -> h1. h1 pixel p covers conv-res coords (ty0-1+hy, tx0-1+hx).
  for (int round = 0; round < 2; ++round){
    int p = round*256 + tid;
    if (p < 324) {
      int hy = p/18, hx = p - hy*18;
      int gy = ty0 - 1 + hy, gx = tx0 - 1 + hx;
      bool valid = (gy >= 0) & (gy < S) & (gx >= 0) & (gx < S);
      float acc[64];
      #pragma unroll
      for (int oc = 0; oc < 64; ++oc) acc[oc] = bias1[oc];
      if (valid) {
        for (int ic = 0; ic < 64; ++ic){
          const float* xc = xb + ic*16384;
          float a[9];
          #pragma unroll
          for (int t = 0; t < 9; ++t){
            int sy = gy + t/3 - 1, sx = gx + t%3 - 1;
            float v = 0.f;
            if (sy >= 0 && sy < S && sx >= 0 && sx < S){
              if (TYPE == 0)      v = xc[sy*128 + sx];
              else if (TYPE == 1) v = xc[(sy>>1)*128 + (sx>>1)];
              else {
                const float* q = xc + (sy*2)*128 + sx*2;
                v = fmaxf(fmaxf(q[0], q[1]), fmaxf(q[128], q[129]));
              }
            }
            a[t] = v;
          }
          const float* wp = w1t + ic*576;       // uniform address -> s_load
          #pragma unroll
          for (int t = 0; t < 9; ++t){
            float av = a[t];
            #pragma unroll
            for (int oc = 0; oc < 64; ++oc)
              acc[oc] = fmaf(av, wp[t*64 + oc], acc[oc]);
          }
        }
      }
      #pragma unroll
      for (int oc = 0; oc < 64; ++oc)
        h1[oc][p] = valid ? f2bf(gelu_exact(acc[oc])) : (unsigned short)0;
    }
  }
  __syncthreads();

  // ---- conv2 over h1, one output pixel per thread
  {
    int py = tid >> 4, px = tid & 15;
    float acc[64];
    #pragma unroll
    for (int oc = 0; oc < 64; ++oc) acc[oc] = bias2[oc];
    for (int ic = 0; ic < 64; ++ic){
      float a[9];
      #pragma unroll
      for (int t = 0; t < 9; ++t)
        a[t] = bf2f(h1[ic][(py + t/3)*18 + (px + t%3)]);
      const float* wp = w2t + ic*576;
      #pragma unroll
      for (int t = 0; t < 9; ++t){
        float av = a[t];
        #pragma unroll
        for (int oc = 0; oc < 64; ++oc)
          acc[oc] = fmaf(av, wp[t*64 + oc], acc[oc]);
      }
    }

    if (TYPE == 0){
      int gy = ty0 + py, gx = tx0 + px;
      float* ob = out + (size_t)b*64*16384 + gy*128 + gx;
      #pragma unroll
      for (int oc = 0; oc < 64; ++oc)
        ob[oc*16384] += g*acc[oc];
    } else if (TYPE == 1){
      // maxpool 2x2 via cross-lane max, then gated accumulate at 128-res
      int gy = ty0 + py, gx = tx0 + px;
      float* ob = out + (size_t)b*64*16384 + (gy>>1)*128 + (gx>>1);
      bool wr = ((px & 1) == 0) && ((py & 1) == 0);
      #pragma unroll
      for (int oc = 0; oc < 64; ++oc){
        float v = acc[oc];
        v = fmaxf(v, __shfl_xor(v, 1));    // horizontal pair (px bit0 == lane bit0)
        v = fmaxf(v, __shfl_xor(v, 16));   // vertical pair   (py bit0 == lane bit4)
        if (wr) ob[oc*16384] += g*v;
      }
    } else {
      // nearest-neighbor 2x upsample: each conv pixel -> 2x2 block at 128-res
      int gy = (ty0 + py)*2, gx = (tx0 + px)*2;
      float* ob = out + (size_t)b*64*16384 + gy*128 + gx;
      #pragma unroll
      for (int oc = 0; oc < 64; ++oc){
        float v = g*acc[oc];
        float* o = ob + oc*16384;
        o[0]   += v; o[1]   += v;
        o[128] += v; o[129] += v;
      }
    }
  }
}

extern "C" void kernel_launch(void* const* d_in, const int* in_sizes, int n_in,
                              void* d_out, int out_size, void* d_ws, size_t ws_size,
                              hipStream_t stream) {
  (void)in_sizes; (void)n_in; (void)ws_size;
  const float* x  = (const float*)d_in[0];
  const float* tf = (const float*)d_in[1];
  const float* Wx = (const float*)d_in[2];
  const float* Wt = (const float*)d_in[3];
  const float* bg = (const float*)d_in[4];
  const float* W1 = (const float*)d_in[5];
  const float* b1 = (const float*)d_in[6];
  const float* W2 = (const float*)d_in[7];
  const float* b2 = (const float*)d_in[8];
  float* out = (float*)d_out;
  float* ws  = (float*)d_ws;

  hipMemsetAsync(d_out, 0, (size_t)out_size*sizeof(float), stream);
  wtrans_kernel<<<4608, 256, 0, stream>>>(W1, W2, ws);
  pool_kernel<<<1024, 256, 0, stream>>>(x, ws);
  gate_kernel<<<1, 256, 0, stream>>>(tf, Wx, Wt, bg, ws, out + 16777216);

  for (int e = 0; e < 16; ++e){
    int t = e % 3;
    if (t == 0)
      expert_kernel<0><<<dim3(64, 16), 256, 0, stream>>>(x, ws, b1, b2, out, e);
    else if (t == 1)
      expert_kernel<1><<<dim3(256, 16), 256, 0, stream>>>(x, ws, b1, b2, out, e);
    else
      expert_kernel<2><<<dim3(16, 16), 256, 0, stream>>>(x, ws, b1, b2, out, e);
  }
}

// Round 3
// 4420.090 us; speedup vs baseline: 2.1053x; 2.1053x over previous
//
#include <hip/hip_runtime.h>
#include <cstdint>
#include <cstddef>

// ---------------- ws layout (float elements) ----------------
// w1t: [16][64][9][64]  (e, ic, tap, oc)   589824 floats
// w2t: same                                589824 floats
// xp : [16][64]                            1024 floats
// gates: [16][16]                          256 floats
#define W1T_OFF   0
#define W2T_OFF   589824
#define XP_OFF    (589824*2)
#define GATES_OFF (XP_OFF + 1024)

__device__ __forceinline__ float bf2f(unsigned short h){
  return __uint_as_float(((uint32_t)h)<<16);
}
__device__ __forceinline__ unsigned short f2bf(float f){
  uint32_t u = __float_as_uint(f);
  u = u + 0x7fffu + ((u>>16)&1u);   // RNE
  return (unsigned short)(u>>16);
}
__device__ __forceinline__ float gelu_exact(float x){
  return 0.5f*x*(1.0f + erff(x*0.70710678118654752440f));
}

// ---------------- weight transpose: W[e][oc][ic][3][3] -> wT[e][ic][tap][oc]
__global__ __launch_bounds__(256) void wtrans_kernel(const float* __restrict__ W1,
                                                     const float* __restrict__ W2,
                                                     float* __restrict__ ws){
  int idx = blockIdx.x*256 + threadIdx.x;      // 0 .. 1,179,647
  const int N = 589824;
  int which = (idx >= N) ? 1 : 0;
  int i = idx - which*N;
  int oc = i & 63;
  int t  = (i>>6) % 9;
  int ic = (i/576) & 63;
  int e  = i/36864;
  const float* src = which ? W2 : W1;
  float v = src[(((e*64 + oc)*64 + ic)*9) + t];
  ws[(which ? W2T_OFF : W1T_OFF) + i] = v;
}

// ---------------- mean pool: xp[b][c] = mean_{h,w} x[b][c][h][w]
__global__ __launch_bounds__(256) void pool_kernel(const float* __restrict__ x,
                                                   float* __restrict__ ws){
  int bc = blockIdx.x;                        // 0..1023
  const float* p = x + (size_t)bc*16384;
  int tid = threadIdx.x;
  float s = 0.f;
  for (int i = tid; i < 16384; i += 256) s += p[i];
  for (int off = 32; off; off >>= 1) s += __shfl_down(s, off);
  __shared__ float r[4];
  if ((tid & 63) == 0) r[tid>>6] = s;
  __syncthreads();
  if (tid == 0) ws[XP_OFF + bc] = (r[0]+r[1]+r[2]+r[3]) * (1.0f/16384.0f);
}

// ---------------- gating: logits -> softmax -> top2 -> gates + aux
__global__ __launch_bounds__(256) void gate_kernel(const float* __restrict__ tf,
    const float* __restrict__ Wx, const float* __restrict__ Wt,
    const float* __restrict__ bg, float* __restrict__ ws,
    float* __restrict__ out_aux){
  __shared__ float lg[16][16];
  __shared__ float gsh[16][16];
  int tid = threadIdx.x;
  int b = tid >> 4, e = tid & 15;
  const float* xp = ws + XP_OFF;
  float acc = bg[e];
  for (int c = 0; c < 64;  ++c) acc += xp[b*64 + c] * Wx[c*16 + e];
  for (int d = 0; d < 512; ++d) acc += tf[b*512 + d] * Wt[d*16 + e];
  lg[b][e] = acc;
  __syncthreads();
  if (tid < 16) {
    int bb = tid;
    float m = -1e30f;
    for (int j = 0; j < 16; ++j) m = fmaxf(m, lg[bb][j]);
    float pr[16]; float s = 0.f;
    for (int j = 0; j < 16; ++j){ pr[j] = expf(lg[bb][j] - m); s += pr[j]; }
    float invs = 1.f/s;
    for (int j = 0; j < 16; ++j) pr[j] *= invs;
    int i1 = 0; float v1 = pr[0];
    for (int j = 1; j < 16; ++j) if (pr[j] > v1){ v1 = pr[j]; i1 = j; }
    float v2 = -1.f; int i2 = 0;
    for (int j = 0; j < 16; ++j) if (j != i1 && pr[j] > v2){ v2 = pr[j]; i2 = j; }
    float inv = 1.f/(v1 + v2);
    for (int j = 0; j < 16; ++j) gsh[bb][j] = 0.f;
    gsh[bb][i1] = v1*inv;
    gsh[bb][i2] = v2*inv;
    for (int j = 0; j < 16; ++j) ws[GATES_OFF + bb*16 + j] = gsh[bb][j];
  }
  __syncthreads();
  if (tid == 0){
    float imp[16]; float mean = 0.f;
    for (int j = 0; j < 16; ++j){
      float t = 0.f;
      for (int bb = 0; bb < 16; ++bb) t += gsh[bb][j];
      imp[j] = t; mean += t;
    }
    mean *= (1.f/16.f);
    float m2 = 0.f;
    for (int j = 0; j < 16; ++j){ float d = imp[j] - mean; m2 += d*d; }
    float var = m2 * (1.f/16.f);
    out_aux[0] = var / (mean*mean + 1e-10f);
  }
}

// ---------------- fused expert tile: conv3x3 -> GELU -> conv3x3 (+resample)
// TYPE 0: full res (S=128). TYPE 1: up2 -> block(S=256) -> maxpool2.
// TYPE 2: maxpool2 -> block(S=64) -> up2.
// Accumulates into out with atomicAdd (two experts per sample run concurrently).
template<int TYPE>
__device__ __forceinline__ void expert_tile(
    const float* __restrict__ x, const float* __restrict__ ws,
    const float* __restrict__ b1, const float* __restrict__ b2,
    float* __restrict__ out, int e, int b, int tile, float g,
    unsigned short (*h1)[324])
{
  constexpr int S = (TYPE==0) ? 128 : ((TYPE==1) ? 256 : 64);
  constexpr int TILES = S/16;
  const int ty0 = (tile / TILES)*16;
  const int tx0 = (tile % TILES)*16;
  const int tid = threadIdx.x;

  const float* w1t  = ws + W1T_OFF + e*36864;  // [ic][tap][oc]
  const float* w2t  = ws + W2T_OFF + e*36864;
  const float* bias1 = b1 + e*64;
  const float* bias2 = b2 + e*64;
  const float* xb = x + (size_t)b*64*16384;

  // ---- conv1 + GELU -> h1 (18x18 halo tile), bf16 in LDS
  for (int round = 0; round < 2; ++round){
    int p = round*256 + tid;
    if (p < 324) {
      int hy = p/18, hx = p - hy*18;
      int gy = ty0 - 1 + hy, gx = tx0 - 1 + hx;
      bool valid = (gy >= 0) & (gy < S) & (gx >= 0) & (gx < S);
      float acc[64];
      #pragma unroll
      for (int oc = 0; oc < 64; ++oc) acc[oc] = bias1[oc];
      if (valid) {
        for (int ic = 0; ic < 64; ++ic){
          const float* xc = xb + ic*16384;
          float a[9];
          #pragma unroll
          for (int t = 0; t < 9; ++t){
            int sy = gy + t/3 - 1, sx = gx + t%3 - 1;
            float v = 0.f;
            if (sy >= 0 && sy < S && sx >= 0 && sx < S){
              if (TYPE == 0)      v = xc[sy*128 + sx];
              else if (TYPE == 1) v = xc[(sy>>1)*128 + (sx>>1)];
              else {
                const float* q = xc + (sy*2)*128 + sx*2;
                v = fmaxf(fmaxf(q[0], q[1]), fmaxf(q[128], q[129]));
              }
            }
            a[t] = v;
          }
          const float* wp = w1t + ic*576;       // wave-uniform address
          #pragma unroll
          for (int t = 0; t < 9; ++t){
            float av = a[t];
            #pragma unroll
            for (int oc = 0; oc < 64; ++oc)
              acc[oc] = fmaf(av, wp[t*64 + oc], acc[oc]);
          }
        }
      }
      #pragma unroll
      for (int oc = 0; oc < 64; ++oc)
        h1[oc][p] = valid ? f2bf(gelu_exact(acc[oc])) : (unsigned short)0;
    }
  }
  __syncthreads();

  // ---- conv2 over h1, one output pixel per thread
  {
    int py = tid >> 4, px = tid & 15;
    float acc[64];
    #pragma unroll
    for (int oc = 0; oc < 64; ++oc) acc[oc] = bias2[oc];
    for (int ic = 0; ic < 64; ++ic){
      float a[9];
      #pragma unroll
      for (int t = 0; t < 9; ++t)
        a[t] = bf2f(h1[ic][(py + t/3)*18 + (px + t%3)]);
      const float* wp = w2t + ic*576;
      #pragma unroll
      for (int t = 0; t < 9; ++t){
        float av = a[t];
        #pragma unroll
        for (int oc = 0; oc < 64; ++oc)
          acc[oc] = fmaf(av, wp[t*64 + oc], acc[oc]);
      }
    }

    if (TYPE == 0){
      int gy = ty0 + py, gx = tx0 + px;
      float* ob = out + (size_t)b*64*16384 + gy*128 + gx;
      #pragma unroll
      for (int oc = 0; oc < 64; ++oc)
        atomicAdd(ob + oc*16384, g*acc[oc]);
    } else if (TYPE == 1){
      // maxpool 2x2 via cross-lane max, then gated accumulate at 128-res
      int gy = ty0 + py, gx = tx0 + px;
      float* ob = out + (size_t)b*64*16384 + (gy>>1)*128 + (gx>>1);
      bool wr = ((px & 1) == 0) && ((py & 1) == 0);
      #pragma unroll
      for (int oc = 0; oc < 64; ++oc){
        float v = acc[oc];
        v = fmaxf(v, __shfl_xor(v, 1));    // horizontal pair (px bit0 == lane bit0)
        v = fmaxf(v, __shfl_xor(v, 16));   // vertical pair   (py bit0 == lane bit4)
        if (wr) atomicAdd(ob + oc*16384, g*v);
      }
    } else {
      // nearest-neighbor 2x upsample: each conv pixel -> 2x2 block at 128-res
      int gy = (ty0 + py)*2, gx = (tx0 + px)*2;
      float* ob = out + (size_t)b*64*16384 + gy*128 + gx;
      #pragma unroll
      for (int oc = 0; oc < 64; ++oc){
        float v = g*acc[oc];
        float* o = ob + oc*16384;
        atomicAdd(o,       v); atomicAdd(o + 1,   v);
        atomicAdd(o + 128, v); atomicAdd(o + 129, v);
      }
    }
  }
}

// ---------------- merged MoE kernel: one launch covers all (expert, sample, tile)
// Per sample, blockIdx.x layout:
//   [0,384):        TYPE0, e = 3*(i/64),        tile = i%64   (8x8 tiles)
//   [384,1664):     TYPE1, e = 3*((i-384)/256)+1, tile = (i-384)%256 (16x16 tiles)
//   [1664,1744):    TYPE2, e = 3*((i-1664)/16)+2, tile = (i-1664)%16 (4x4 tiles)
__global__ __launch_bounds__(256) void moe_kernel(
    const float* __restrict__ x, const float* __restrict__ ws,
    const float* __restrict__ b1, const float* __restrict__ b2,
    float* __restrict__ out)
{
  __shared__ unsigned short h1[64][324];
  const int b = blockIdx.y;
  const int i = blockIdx.x;
  int e, tile, type;
  if (i < 384)       { type = 0; e = 3*(i>>6);            tile = i & 63;  }
  else if (i < 1664) { type = 1; e = 3*((i-384)>>8) + 1;  tile = (i-384) & 255; }
  else               { type = 2; e = 3*((i-1664)>>4) + 2; tile = (i-1664) & 15; }

  const float g = ws[GATES_OFF + b*16 + e];
  if (g == 0.0f) return;                       // inactive expert for this sample

  if (type == 0)      expert_tile<0>(x, ws, b1, b2, out, e, b, tile, g, h1);
  else if (type == 1) expert_tile<1>(x, ws, b1, b2, out, e, b, tile, g, h1);
  else                expert_tile<2>(x, ws, b1, b2, out, e, b, tile, g, h1);
}

extern "C" void kernel_launch(void* const* d_in, const int* in_sizes, int n_in,
                              void* d_out, int out_size, void* d_ws, size_t ws_size,
                              hipStream_t stream) {
  (void)in_sizes; (void)n_in; (void)ws_size;
  const float* x  = (const float*)d_in[0];
  const float* tf = (const float*)d_in[1];
  const float* Wx = (const float*)d_in[2];
  const float* Wt = (const float*)d_in[3];
  const float* bg = (const float*)d_in[4];
  const float* W1 = (const float*)d_in[5];
  const float* b1 = (const float*)d_in[6];
  const float* W2 = (const float*)d_in[7];
  const float* b2 = (const float*)d_in[8];
  float* out = (float*)d_out;
  float* ws  = (float*)d_ws;

  hipMemsetAsync(d_out, 0, (size_t)out_size*sizeof(float), stream);
  wtrans_kernel<<<4608, 256, 0, stream>>>(W1, W2, ws);
  pool_kernel<<<1024, 256, 0, stream>>>(x, ws);
  gate_kernel<<<1, 256, 0, stream>>>(tf, Wx, Wt, bg, ws, out + 16777216);

  moe_kernel<<<dim3(1744, 16), 256, 0, stream>>>(x, ws, b1, b2, out);
}

// Round 4
// 827.694 us; speedup vs baseline: 11.2427x; 5.3402x over previous
//
#include <hip/hip_runtime.h>
#include <cstdint>
#include <cstddef>

typedef __bf16 bf16x8 __attribute__((ext_vector_type(8)));
typedef float f32x4 __attribute__((ext_vector_type(4)));

// ---------------- ws layout ----------------
// bytes [0, 2359296): wt bf16 [16][2][9][64(oc)][64(ic)]   (1,179,648 ushorts)
// float offset 589824: xp [16][64]
// float offset 590848: gates [16][16]
#define XP_OFF_F    589824
#define GATES_OFF_F 590848

__device__ __forceinline__ unsigned short f2bf(float f){
  uint32_t u = __float_as_uint(f);
  u = u + 0x7fffu + ((u>>16)&1u);   // RNE
  return (unsigned short)(u>>16);
}
__device__ __forceinline__ float gelu_exact(float x){
  return 0.5f*x*(1.0f + erff(x*0.70710678118654752440f));
}

// ---------------- weight transpose+cast: W[e][oc][ic][3][3] -> wt[e][c][tap][oc][ic] bf16
__global__ __launch_bounds__(256) void wtrans_kernel(const float* __restrict__ W1,
                                                     const float* __restrict__ W2,
                                                     unsigned short* __restrict__ wt){
  int idx = blockIdx.x*256 + threadIdx.x;      // 0 .. 1,179,647
  int ic  = idx & 63;
  int oc  = (idx>>6) & 63;
  int tap = (idx>>12) % 9;
  int ec  = idx / 36864;                       // e*2 + c
  int e = ec >> 1, c = ec & 1;
  const float* src = c ? W2 : W1;
  wt[idx] = f2bf(src[((e*64 + oc)*64 + ic)*9 + tap]);
}

// ---------------- mean pool: xp[b][c] = mean_{h,w} x[b][c][h][w]
__global__ __launch_bounds__(256) void pool_kernel(const float* __restrict__ x,
                                                   float* __restrict__ wsf){
  int bc = blockIdx.x;                        // 0..1023
  const float* p = x + (size_t)bc*16384;
  int tid = threadIdx.x;
  float s = 0.f;
  for (int i = tid; i < 16384; i += 256) s += p[i];
  for (int off = 32; off; off >>= 1) s += __shfl_down(s, off);
  __shared__ float r[4];
  if ((tid & 63) == 0) r[tid>>6] = s;
  __syncthreads();
  if (tid == 0) wsf[XP_OFF_F + bc] = (r[0]+r[1]+r[2]+r[3]) * (1.0f/16384.0f);
}

// ---------------- gating: logits -> softmax -> top2 -> gates + aux
__global__ __launch_bounds__(256) void gate_kernel(const float* __restrict__ tf,
    const float* __restrict__ Wx, const float* __restrict__ Wt,
    const float* __restrict__ bg, float* __restrict__ wsf,
    float* __restrict__ out_aux){
  __shared__ float lg[16][16];
  __shared__ float gsh[16][16];
  int tid = threadIdx.x;
  int b = tid >> 4, e = tid & 15;
  const float* xp = wsf + XP_OFF_F;
  float acc = bg[e];
  for (int c = 0; c < 64;  ++c) acc += xp[b*64 + c] * Wx[c*16 + e];
  for (int d = 0; d < 512; ++d) acc += tf[b*512 + d] * Wt[d*16 + e];
  lg[b][e] = acc;
  __syncthreads();
  if (tid < 16) {
    int bb = tid;
    float m = -1e30f;
    for (int j = 0; j < 16; ++j) m = fmaxf(m, lg[bb][j]);
    float pr[16]; float s = 0.f;
    for (int j = 0; j < 16; ++j){ pr[j] = expf(lg[bb][j] - m); s += pr[j]; }
    float invs = 1.f/s;
    for (int j = 0; j < 16; ++j) pr[j] *= invs;
    int i1 = 0; float v1 = pr[0];
    for (int j = 1; j < 16; ++j) if (pr[j] > v1){ v1 = pr[j]; i1 = j; }
    float v2 = -1.f; int i2 = 0;
    for (int j = 0; j < 16; ++j) if (j != i1 && pr[j] > v2){ v2 = pr[j]; i2 = j; }
    float inv = 1.f/(v1 + v2);
    for (int j = 0; j < 16; ++j) gsh[bb][j] = 0.f;
    gsh[bb][i1] = v1*inv;
    gsh[bb][i2] = v2*inv;
    for (int j = 0; j < 16; ++j) wsf[GATES_OFF_F + bb*16 + j] = gsh[bb][j];
  }
  __syncthreads();
  if (tid == 0){
    float imp[16]; float mean = 0.f;
    for (int j = 0; j < 16; ++j){
      float t = 0.f;
      for (int bb = 0; bb < 16; ++bb) t += gsh[bb][j];
      imp[j] = t; mean += t;
    }
    mean *= (1.f/16.f);
    float m2 = 0.f;
    for (int j = 0; j < 16; ++j){ float d = imp[j] - mean; m2 += d*d; }
    float var = m2 * (1.f/16.f);
    out_aux[0] = var / (mean*mean + 1e-10f);
  }
}

// ---------------- fused MFMA expert tile ----------------
// TYPE 0: full res (S=128). TYPE 1: up2 -> block(S=256) -> maxpool2.
// TYPE 2: maxpool2 -> block(S=64) -> up2.
// conv as tap-decomposed GEMM on mfma_f32_16x16x32_bf16.
// LDS: xs[400][64] bf16 (20x20 input halo, pixel-major, XOR-swizzled),
//      reused for h1[324][64] after conv1.
template<int TYPE>
__device__ __forceinline__ void expert_tile(
    const float* __restrict__ x, const unsigned short* __restrict__ wt,
    const float* __restrict__ b1, const float* __restrict__ b2,
    float* __restrict__ out, int e, int b, int tile, float g,
    unsigned short* xs)
{
  constexpr int S = (TYPE==0) ? 128 : ((TYPE==1) ? 256 : 64);
  constexpr int TILES = S/16;
  const int ty0 = (tile / TILES)*16;
  const int tx0 = (tile % TILES)*16;
  const int tid  = threadIdx.x;
  const int lane = tid & 63;
  const int wid  = tid >> 6;
  const int lr   = lane & 15;          // A-row / B-col / C-col index
  const int kg   = (lane >> 4) * 8;    // k-subgroup offset

  const unsigned short* wt1 = wt + (size_t)(e*2 + 0)*9*4096;
  const unsigned short* wt2 = wt + (size_t)(e*2 + 1)*9*4096;
  const float* xb = x + (size_t)b*64*16384;

  // ---- stage 20x20x64 input halo -> xs (bf16, swizzled), per-pixel 8x b128 writes
  for (int r = 0; r < 2; ++r){
    int p = r*256 + tid;
    if (p < 400){
      int hy = p/20, hx = p - hy*20;
      int sy = ty0 - 2 + hy, sx = tx0 - 2 + hx;      // conv-res coords
      bool valid = (sy >= 0) & (sy < S) & (sx >= 0) & (sx < S);
      int sw = (p & 7) * 8;
      #pragma unroll
      for (int icb = 0; icb < 8; ++icb){
        union { unsigned short u[8]; uint4 v; } pk;
        if (valid){
          #pragma unroll
          for (int j = 0; j < 8; ++j){
            const float* xc = xb + (icb*8 + j)*16384;
            float v;
            if (TYPE == 0)      v = xc[sy*128 + sx];
            else if (TYPE == 1) v = xc[(sy>>1)*128 + (sx>>1)];
            else {
              const float* q = xc + sy*256 + sx*2;
              v = fmaxf(fmaxf(q[0], q[1]), fmaxf(q[128], q[129]));
            }
            pk.u[j] = f2bf(v);
          }
        } else {
          pk.v = make_uint4(0,0,0,0);
        }
        *reinterpret_cast<uint4*>(&xs[p*64 + ((icb*8) ^ sw)]) = pk.v;
      }
    }
  }

  // per-lane bias fragments
  float bias1v[4], bias2v[4];
  #pragma unroll
  for (int nt = 0; nt < 4; ++nt){
    bias1v[nt] = b1[e*64 + nt*16 + lr];
    bias2v[nt] = b2[e*64 + nt*16 + lr];
  }

  // conv1 m-fragment pixel bases (24 frags of 16 over 324 h1 pixels, clamped)
  int qb1[6];
  #pragma unroll
  for (int i = 0; i < 6; ++i){
    int q = (wid*6 + i)*16 + lr;
    q = q > 323 ? 323 : q;
    qb1[i] = (q/18)*20 + (q%18);
  }

  __syncthreads();

  // ---- conv1: h1[324][64] = x (*) W1, tap-decomposed MFMA GEMM
  f32x4 acc1[6][4];
  #pragma unroll
  for (int i = 0; i < 6; ++i)
    #pragma unroll
    for (int nt = 0; nt < 4; ++nt)
      acc1[i][nt] = (f32x4){0.f,0.f,0.f,0.f};

  for (int tap = 0; tap < 9; ++tap){
    int poff = (tap/3)*20 + (tap%3);
    #pragma unroll
    for (int kf = 0; kf < 2; ++kf){
      int icb = kf*32 + kg;
      const unsigned short* wb = wt1 + tap*4096 + lr*64 + icb;
      bf16x8 bfr[4];
      #pragma unroll
      for (int nt = 0; nt < 4; ++nt)
        bfr[nt] = *reinterpret_cast<const bf16x8*>(wb + nt*1024);
      #pragma unroll
      for (int i = 0; i < 6; ++i){
        int p = qb1[i] + poff;
        bf16x8 a = *reinterpret_cast<const bf16x8*>(&xs[p*64 + (icb ^ ((p&7)*8))]);
        #pragma unroll
        for (int nt = 0; nt < 4; ++nt)
          acc1[i][nt] = __builtin_amdgcn_mfma_f32_16x16x32_bf16(a, bfr[nt], acc1[i][nt], 0, 0, 0);
      }
    }
  }

  __syncthreads();   // all xs reads done; safe to overwrite with h1

  // ---- bias + GELU -> h1 (zero outside image: reference zero-pads h1)
  #pragma unroll
  for (int i = 0; i < 6; ++i){
    int mf = wid*6 + i;
    #pragma unroll
    for (int j = 0; j < 4; ++j){
      int q = mf*16 + (lane>>4)*4 + j;
      if (q < 324){
        int qy = q/18, qx = q - qy*18;
        int gy = ty0 - 1 + qy, gx = tx0 - 1 + qx;
        bool in_img = (gy >= 0) & (gy < S) & (gx >= 0) & (gx < S);
        int sw = (q & 7) * 8;
        #pragma unroll
        for (int nt = 0; nt < 4; ++nt){
          float v = in_img ? gelu_exact(acc1[i][nt][j] + bias1v[nt]) : 0.f;
          xs[q*64 + ((nt*16 + lr) ^ sw)] = f2bf(v);
        }
      }
    }
  }

  __syncthreads();

  // ---- conv2: out[256][64] = h1 (*) W2
  f32x4 acc2[4][4];
  #pragma unroll
  for (int i = 0; i < 4; ++i)
    #pragma unroll
    for (int nt = 0; nt < 4; ++nt)
      acc2[i][nt] = (f32x4){0.f,0.f,0.f,0.f};

  for (int tap = 0; tap < 9; ++tap){
    int dy = tap/3, dx = tap - dy*3;
    #pragma unroll
    for (int kf = 0; kf < 2; ++kf){
      int icb = kf*32 + kg;
      const unsigned short* wb = wt2 + tap*4096 + lr*64 + icb;
      bf16x8 bfr[4];
      #pragma unroll
      for (int nt = 0; nt < 4; ++nt)
        bfr[nt] = *reinterpret_cast<const bf16x8*>(wb + nt*1024);
      #pragma unroll
      for (int i = 0; i < 4; ++i){
        int p = (wid*4 + i + dy)*18 + lr + dx;
        bf16x8 a = *reinterpret_cast<const bf16x8*>(&xs[p*64 + (icb ^ ((p&7)*8))]);
        #pragma unroll
        for (int nt = 0; nt < 4; ++nt)
          acc2[i][nt] = __builtin_amdgcn_mfma_f32_16x16x32_bf16(a, bfr[nt], acc2[i][nt], 0, 0, 0);
      }
    }
  }

  // ---- epilogue: bias + gate + resample + atomic accumulate
  // C/D layout: oc = nt*16 + lr; out-pixel py = wid*4 + i, px = (lane>>4)*4 + j
  const size_t ob = (size_t)b*1048576;
  if (TYPE == 0){
    #pragma unroll
    for (int i = 0; i < 4; ++i){
      int py = wid*4 + i;
      #pragma unroll
      for (int nt = 0; nt < 4; ++nt){
        int oc = nt*16 + lr;
        float* o = out + ob + (size_t)oc*16384 + (ty0+py)*128 + tx0;
        #pragma unroll
        for (int j = 0; j < 4; ++j){
          int px = (lane>>4)*4 + j;
          atomicAdd(o + px, g*(acc2[i][nt][j] + bias2v[nt]));
        }
      }
    }
  } else if (TYPE == 1){
    // 2x2 maxpool fully in-lane: px pairs = j pairs, py pairs = i pairs
    #pragma unroll
    for (int i2 = 0; i2 < 2; ++i2){
      int Py = (ty0 + wid*4 + 2*i2) >> 1;
      #pragma unroll
      for (int nt = 0; nt < 4; ++nt){
        int oc = nt*16 + lr;
        float bb = bias2v[nt];
        #pragma unroll
        for (int j2 = 0; j2 < 2; ++j2){
          float m = fmaxf(fmaxf(acc2[2*i2][nt][2*j2],   acc2[2*i2][nt][2*j2+1]),
                          fmaxf(acc2[2*i2+1][nt][2*j2], acc2[2*i2+1][nt][2*j2+1]));
          int Px = (tx0 + (lane>>4)*4 + 2*j2) >> 1;
          atomicAdd(out + ob + (size_t)oc*16384 + Py*128 + Px, g*(m + bb));
        }
      }
    }
  } else {
    // nearest 2x upsample: each conv pixel -> 2x2 block at 128-res
    #pragma unroll
    for (int i = 0; i < 4; ++i){
      int gy = (ty0 + wid*4 + i)*2;
      #pragma unroll
      for (int nt = 0; nt < 4; ++nt){
        int oc = nt*16 + lr;
        #pragma unroll
        for (int j = 0; j < 4; ++j){
          int gx = (tx0 + (lane>>4)*4 + j)*2;
          float v = g*(acc2[i][nt][j] + bias2v[nt]);
          float* o = out + ob + (size_t)oc*16384 + gy*128 + gx;
          atomicAdd(o,       v); atomicAdd(o + 1,   v);
          atomicAdd(o + 128, v); atomicAdd(o + 129, v);
        }
      }
    }
  }
}

// ---------------- merged MoE kernel ----------------
// Per sample, blockIdx.x layout:
//   [0,384):     TYPE0, e = 3*(i/64),          tile = i%64   (8x8 tiles)
//   [384,1664):  TYPE1, e = 3*((i-384)/256)+1, tile = (i-384)%256 (16x16 tiles)
//   [1664,1744): TYPE2, e = 3*((i-1664)/16)+2, tile = (i-1664)%16 (4x4 tiles)
__global__ __launch_bounds__(256, 3) void moe_kernel(
    const float* __restrict__ x, const unsigned short* __restrict__ wt,
    const float* __restrict__ wsf,
    const float* __restrict__ b1, const float* __restrict__ b2,
    float* __restrict__ out)
{
  __shared__ unsigned short xs[25600];   // 50 KB: input halo, then h1
  const int b = blockIdx.y;
  const int i = blockIdx.x;
  int e, tile, type;
  if (i < 384)       { type = 0; e = 3*(i>>6);            tile = i & 63;  }
  else if (i < 1664) { type = 1; e = 3*((i-384)>>8) + 1;  tile = (i-384) & 255; }
  else               { type = 2; e = 3*((i-1664)>>4) + 2; tile = (i-1664) & 15; }

  const float g = wsf[GATES_OFF_F + b*16 + e];
  if (g == 0.0f) return;                 // inactive expert for this sample

  if (type == 0)      expert_tile<0>(x, wt, b1, b2, out, e, b, tile, g, xs);
  else if (type == 1) expert_tile<1>(x, wt, b1, b2, out, e, b, tile, g, xs);
  else                expert_tile<2>(x, wt, b1, b2, out, e, b, tile, g, xs);
}

extern "C" void kernel_launch(void* const* d_in, const int* in_sizes, int n_in,
                              void* d_out, int out_size, void* d_ws, size_t ws_size,
                              hipStream_t stream) {
  (void)in_sizes; (void)n_in; (void)ws_size;
  const float* x  = (const float*)d_in[0];
  const float* tf = (const float*)d_in[1];
  const float* Wx = (const float*)d_in[2];
  const float* Wt = (const float*)d_in[3];
  const float* bg = (const float*)d_in[4];
  const float* W1 = (const float*)d_in[5];
  const float* b1 = (const float*)d_in[6];
  const float* W2 = (const float*)d_in[7];
  const float* b2 = (const float*)d_in[8];
  float* out = (float*)d_out;
  unsigned short* wt = (unsigned short*)d_ws;
  float* wsf = (float*)d_ws;

  hipMemsetAsync(d_out, 0, (size_t)out_size*sizeof(float), stream);
  wtrans_kernel<<<4608, 256, 0, stream>>>(W1, W2, wt);
  pool_kernel<<<1024, 256, 0, stream>>>(x, wsf);
  gate_kernel<<<1, 256, 0, stream>>>(tf, Wx, Wt, bg, wsf, out + 16777216);

  moe_kernel<<<dim3(1744, 16), 256, 0, stream>>>(x, wt, wsf, b1, b2, out);
}

// Round 5
// 822.435 us; speedup vs baseline: 11.3146x; 1.0064x over previous
//
#include <hip/hip_runtime.h>
#include <cstdint>
#include <cstddef>

typedef __bf16 bf16x8 __attribute__((ext_vector_type(8)));
typedef float f32x4 __attribute__((ext_vector_type(4)));

// ---------------- ws layout ----------------
// bytes [0, 2359296): wt bf16 [16][2][9][64(oc)][64(ic)]
// float offset 589824: xp [16][64]; float offset 590848: gates [16][16]
// bytes [4MB, 4MB+33554432): xt bf16 [16][16384(pixel)][64(ch)]  (NHWC)
#define XP_OFF_F    589824
#define GATES_OFF_F 590848
#define XT_OFF_B    (4u<<20)

__device__ __forceinline__ float bf2f(unsigned short h){
  return __uint_as_float(((uint32_t)h)<<16);
}
__device__ __forceinline__ unsigned short f2bf(float f){
  uint32_t u = __float_as_uint(f);
  u = u + 0x7fffu + ((u>>16)&1u);   // RNE
  return (unsigned short)(u>>16);
}
__device__ __forceinline__ float gelu_exact(float x){
  return 0.5f*x*(1.0f + erff(x*0.70710678118654752440f));
}

// ---------------- weight transpose+cast: W[e][oc][ic][3][3] -> wt[e][c][tap][oc][ic] bf16
__global__ __launch_bounds__(256) void wtrans_kernel(const float* __restrict__ W1,
                                                     const float* __restrict__ W2,
                                                     unsigned short* __restrict__ wt){
  int idx = blockIdx.x*256 + threadIdx.x;      // 0 .. 1,179,647
  int ic  = idx & 63;
  int oc  = (idx>>6) & 63;
  int tap = (idx>>12) % 9;
  int ec  = idx / 36864;                       // e*2 + c
  int e = ec >> 1, c = ec & 1;
  const float* src = c ? W2 : W1;
  wt[idx] = f2bf(src[((e*64 + oc)*64 + ic)*9 + tap]);
}

// ---------------- x NCHW fp32 -> NHWC bf16
__global__ __launch_bounds__(256) void xform_kernel(const float* __restrict__ x,
                                                    unsigned short* __restrict__ xt){
  int b = blockIdx.y;
  int p = blockIdx.x*256 + threadIdx.x;        // 0..16383
  const float* xb = x + (size_t)b*1048576;
  unsigned short v[64];
  #pragma unroll
  for (int c = 0; c < 64; ++c)
    v[c] = f2bf(xb[c*16384 + p]);
  uint4* dst = reinterpret_cast<uint4*>(xt + (size_t)b*1048576 + (size_t)p*64);
  const uint4* src = reinterpret_cast<const uint4*>(v);
  #pragma unroll
  for (int i = 0; i < 8; ++i) dst[i] = src[i];
}

// ---------------- mean pool: xp[b][c] = mean_{h,w} x[b][c][h][w]
__global__ __launch_bounds__(256) void pool_kernel(const float* __restrict__ x,
                                                   float* __restrict__ wsf){
  int bc = blockIdx.x;                        // 0..1023
  const float* p = x + (size_t)bc*16384;
  int tid = threadIdx.x;
  float s = 0.f;
  for (int i = tid; i < 16384; i += 256) s += p[i];
  for (int off = 32; off; off >>= 1) s += __shfl_down(s, off);
  __shared__ float r[4];
  if ((tid & 63) == 0) r[tid>>6] = s;
  __syncthreads();
  if (tid == 0) wsf[XP_OFF_F + bc] = (r[0]+r[1]+r[2]+r[3]) * (1.0f/16384.0f);
}

// ---------------- gating: logits -> softmax -> top2 -> gates + aux
__global__ __launch_bounds__(256) void gate_kernel(const float* __restrict__ tf,
    const float* __restrict__ Wx, const float* __restrict__ Wt,
    const float* __restrict__ bg, float* __restrict__ wsf,
    float* __restrict__ out_aux){
  __shared__ float lg[16][16];
  __shared__ float gsh[16][16];
  int tid = threadIdx.x;
  int b = tid >> 4, e = tid & 15;
  const float* xp = wsf + XP_OFF_F;
  float acc = bg[e];
  for (int c = 0; c < 64;  ++c) acc += xp[b*64 + c] * Wx[c*16 + e];
  for (int d = 0; d < 512; ++d) acc += tf[b*512 + d] * Wt[d*16 + e];
  lg[b][e] = acc;
  __syncthreads();
  if (tid < 16) {
    int bb = tid;
    float m = -1e30f;
    for (int j = 0; j < 16; ++j) m = fmaxf(m, lg[bb][j]);
    float pr[16]; float s = 0.f;
    for (int j = 0; j < 16; ++j){ pr[j] = expf(lg[bb][j] - m); s += pr[j]; }
    float invs = 1.f/s;
    for (int j = 0; j < 16; ++j) pr[j] *= invs;
    int i1 = 0; float v1 = pr[0];
    for (int j = 1; j < 16; ++j) if (pr[j] > v1){ v1 = pr[j]; i1 = j; }
    float v2 = -1.f; int i2 = 0;
    for (int j = 0; j < 16; ++j) if (j != i1 && pr[j] > v2){ v2 = pr[j]; i2 = j; }
    float inv = 1.f/(v1 + v2);
    for (int j = 0; j < 16; ++j) gsh[bb][j] = 0.f;
    gsh[bb][i1] = v1*inv;
    gsh[bb][i2] = v2*inv;
    for (int j = 0; j < 16; ++j) wsf[GATES_OFF_F + bb*16 + j] = gsh[bb][j];
  }
  __syncthreads();
  if (tid == 0){
    float imp[16]; float mean = 0.f;
    for (int j = 0; j < 16; ++j){
      float t = 0.f;
      for (int bb = 0; bb < 16; ++bb) t += gsh[bb][j];
      imp[j] = t; mean += t;
    }
    mean *= (1.f/16.f);
    float m2 = 0.f;
    for (int j = 0; j < 16; ++j){ float d = imp[j] - mean; m2 += d*d; }
    float var = m2 * (1.f/16.f);
    out_aux[0] = var / (mean*mean + 1e-10f);
  }
}

// ---------------- fused MFMA expert tile ----------------
// TYPE 0: full res (S=128). TYPE 1: up2 -> block(S=256) -> maxpool2.
// TYPE 2: maxpool2 -> block(S=64) -> up2.
// conv as tap-decomposed GEMM on mfma_f32_16x16x32_bf16.
// LDS: xs[400][64] bf16 (20x20 input halo, pixel-major, XOR-swizzled),
//      reused for h1[324][64] after conv1. Staging reads NHWC bf16 xt.
template<int TYPE>
__device__ __forceinline__ void expert_tile(
    const unsigned short* __restrict__ xt, const unsigned short* __restrict__ wt,
    const float* __restrict__ b1, const float* __restrict__ b2,
    float* __restrict__ out, int e, int b, int tile, float g,
    unsigned short* xs)
{
  constexpr int S = (TYPE==0) ? 128 : ((TYPE==1) ? 256 : 64);
  constexpr int TILES = S/16;
  const int ty0 = (tile / TILES)*16;
  const int tx0 = (tile % TILES)*16;
  const int tid  = threadIdx.x;
  const int lane = tid & 63;
  const int wid  = tid >> 6;
  const int lr   = lane & 15;          // A-row / B-col / C-col index
  const int kg   = (lane >> 4) * 8;    // k-subgroup offset

  const unsigned short* wt1 = wt + (size_t)(e*2 + 0)*9*4096;
  const unsigned short* wt2 = wt + (size_t)(e*2 + 1)*9*4096;
  const unsigned short* xtb = xt + (size_t)b*1048576;   // [pixel][64]

  // ---- stage 20x20x64 input halo -> xs (bf16, swizzled), vector loads from NHWC
  for (int r = 0; r < 2; ++r){
    int p = r*256 + tid;
    if (p < 400){
      int hy = p/20, hx = p - hy*20;
      int sy = ty0 - 2 + hy, sx = tx0 - 2 + hx;      // conv-res coords
      bool valid = (sy >= 0) & (sy < S) & (sx >= 0) & (sx < S);
      int sw = (p & 7) * 8;
      if (!valid){
        uint4 z = make_uint4(0,0,0,0);
        #pragma unroll
        for (int icb = 0; icb < 8; ++icb)
          *reinterpret_cast<uint4*>(&xs[p*64 + ((icb*8) ^ sw)]) = z;
      } else if (TYPE == 0){
        const uint4* src = reinterpret_cast<const uint4*>(xtb + ((size_t)(sy*128 + sx))*64);
        #pragma unroll
        for (int icb = 0; icb < 8; ++icb)
          *reinterpret_cast<uint4*>(&xs[p*64 + ((icb*8) ^ sw)]) = src[icb];
      } else if (TYPE == 1){
        const uint4* src = reinterpret_cast<const uint4*>(xtb + ((size_t)((sy>>1)*128 + (sx>>1)))*64);
        #pragma unroll
        for (int icb = 0; icb < 8; ++icb)
          *reinterpret_cast<uint4*>(&xs[p*64 + ((icb*8) ^ sw)]) = src[icb];
      } else {
        // 2x2 maxpool on bf16 (exact: RNE is monotone)
        const uint4* q00 = reinterpret_cast<const uint4*>(xtb + ((size_t)(sy*256 + sx*2))*64);
        const uint4* q01 = q00 + 8;          // +1 pixel in x
        const uint4* q10 = q00 + 128*8;      // +1 pixel in y
        const uint4* q11 = q10 + 8;
        #pragma unroll
        for (int icb = 0; icb < 8; ++icb){
          union { unsigned short u[8]; uint4 v; } a0,a1,a2,a3,o;
          a0.v = q00[icb]; a1.v = q01[icb]; a2.v = q10[icb]; a3.v = q11[icb];
          #pragma unroll
          for (int j = 0; j < 8; ++j){
            float m = fmaxf(fmaxf(bf2f(a0.u[j]), bf2f(a1.u[j])),
                            fmaxf(bf2f(a2.u[j]), bf2f(a3.u[j])));
            o.u[j] = f2bf(m);   // exact (m is a bf16 value)
          }
          *reinterpret_cast<uint4*>(&xs[p*64 + ((icb*8) ^ sw)]) = o.v;
        }
      }
    }
  }

  // per-lane bias fragments
  float bias1v[4], bias2v[4];
  #pragma unroll
  for (int nt = 0; nt < 4; ++nt){
    bias1v[nt] = b1[e*64 + nt*16 + lr];
    bias2v[nt] = b2[e*64 + nt*16 + lr];
  }

  // conv1 m-fragment pixel bases (24 frags of 16 over 324 h1 pixels, clamped)
  int qb1[6];
  #pragma unroll
  for (int i = 0; i < 6; ++i){
    int q = (wid*6 + i)*16 + lr;
    q = q > 323 ? 323 : q;
    qb1[i] = (q/18)*20 + (q%18);
  }

  __syncthreads();

  // ---- conv1: h1[324][64] = x (*) W1, tap-decomposed MFMA GEMM
  f32x4 acc1[6][4];
  #pragma unroll
  for (int i = 0; i < 6; ++i)
    #pragma unroll
    for (int nt = 0; nt < 4; ++nt)
      acc1[i][nt] = (f32x4){0.f,0.f,0.f,0.f};

  for (int tap = 0; tap < 9; ++tap){
    int poff = (tap/3)*20 + (tap%3);
    #pragma unroll
    for (int kf = 0; kf < 2; ++kf){
      int icb = kf*32 + kg;
      const unsigned short* wb = wt1 + tap*4096 + lr*64 + icb;
      bf16x8 bfr[4];
      #pragma unroll
      for (int nt = 0; nt < 4; ++nt)
        bfr[nt] = *reinterpret_cast<const bf16x8*>(wb + nt*1024);
      #pragma unroll
      for (int i = 0; i < 6; ++i){
        int p = qb1[i] + poff;
        bf16x8 a = *reinterpret_cast<const bf16x8*>(&xs[p*64 + (icb ^ ((p&7)*8))]);
        #pragma unroll
        for (int nt = 0; nt < 4; ++nt)
          acc1[i][nt] = __builtin_amdgcn_mfma_f32_16x16x32_bf16(a, bfr[nt], acc1[i][nt], 0, 0, 0);
      }
    }
  }

  __syncthreads();   // all xs reads done; safe to overwrite with h1

  // ---- bias + GELU -> h1 (zero outside image: reference zero-pads h1)
  #pragma unroll
  for (int i = 0; i < 6; ++i){
    int mf = wid*6 + i;
    #pragma unroll
    for (int j = 0; j < 4; ++j){
      int q = mf*16 + (lane>>4)*4 + j;
      if (q < 324){
        int qy = q/18, qx = q - qy*18;
        int gy = ty0 - 1 + qy, gx = tx0 - 1 + qx;
        bool in_img = (gy >= 0) & (gy < S) & (gx >= 0) & (gx < S);
        int sw = (q & 7) * 8;
        #pragma unroll
        for (int nt = 0; nt < 4; ++nt){
          float v = in_img ? gelu_exact(acc1[i][nt][j] + bias1v[nt]) : 0.f;
          xs[q*64 + ((nt*16 + lr) ^ sw)] = f2bf(v);
        }
      }
    }
  }

  __syncthreads();

  // ---- conv2: out[256][64] = h1 (*) W2
  f32x4 acc2[4][4];
  #pragma unroll
  for (int i = 0; i < 4; ++i)
    #pragma unroll
    for (int nt = 0; nt < 4; ++nt)
      acc2[i][nt] = (f32x4){0.f,0.f,0.f,0.f};

  for (int tap = 0; tap < 9; ++tap){
    int dy = tap/3, dx = tap - dy*3;
    #pragma unroll
    for (int kf = 0; kf < 2; ++kf){
      int icb = kf*32 + kg;
      const unsigned short* wb = wt2 + tap*4096 + lr*64 + icb;
      bf16x8 bfr[4];
      #pragma unroll
      for (int nt = 0; nt < 4; ++nt)
        bfr[nt] = *reinterpret_cast<const bf16x8*>(wb + nt*1024);
      #pragma unroll
      for (int i = 0; i < 4; ++i){
        int p = (wid*4 + i + dy)*18 + lr + dx;
        bf16x8 a = *reinterpret_cast<const bf16x8*>(&xs[p*64 + (icb ^ ((p&7)*8))]);
        #pragma unroll
        for (int nt = 0; nt < 4; ++nt)
          acc2[i][nt] = __builtin_amdgcn_mfma_f32_16x16x32_bf16(a, bfr[nt], acc2[i][nt], 0, 0, 0);
      }
    }
  }

  // ---- epilogue: bias + gate + resample + atomic accumulate
  // C/D layout: oc = nt*16 + lr; out-pixel py = wid*4 + i, px = (lane>>4)*4 + j
  const size_t ob = (size_t)b*1048576;
  if (TYPE == 0){
    #pragma unroll
    for (int i = 0; i < 4; ++i){
      int py = wid*4 + i;
      #pragma unroll
      for (int nt = 0; nt < 4; ++nt){
        int oc = nt*16 + lr;
        float* o = out + ob + (size_t)oc*16384 + (ty0+py)*128 + tx0;
        #pragma unroll
        for (int j = 0; j < 4; ++j){
          int px = (lane>>4)*4 + j;
          atomicAdd(o + px, g*(acc2[i][nt][j] + bias2v[nt]));
        }
      }
    }
  } else if (TYPE == 1){
    // 2x2 maxpool fully in-lane: px pairs = j pairs, py pairs = i pairs
    #pragma unroll
    for (int i2 = 0; i2 < 2; ++i2){
      int Py = (ty0 + wid*4 + 2*i2) >> 1;
      #pragma unroll
      for (int nt = 0; nt < 4; ++nt){
        int oc = nt*16 + lr;
        float bb = bias2v[nt];
        #pragma unroll
        for (int j2 = 0; j2 < 2; ++j2){
          float m = fmaxf(fmaxf(acc2[2*i2][nt][2*j2],   acc2[2*i2][nt][2*j2+1]),
                          fmaxf(acc2[2*i2+1][nt][2*j2], acc2[2*i2+1][nt][2*j2+1]));
          int Px = (tx0 + (lane>>4)*4 + 2*j2) >> 1;
          atomicAdd(out + ob + (size_t)oc*16384 + Py*128 + Px, g*(m + bb));
        }
      }
    }
  } else {
    // nearest 2x upsample: each conv pixel -> 2x2 block at 128-res
    #pragma unroll
    for (int i = 0; i < 4; ++i){
      int gy = (ty0 + wid*4 + i)*2;
      #pragma unroll
      for (int nt = 0; nt < 4; ++nt){
        int oc = nt*16 + lr;
        #pragma unroll
        for (int j = 0; j < 4; ++j){
          int gx = (tx0 + (lane>>4)*4 + j)*2;
          float v = g*(acc2[i][nt][j] + bias2v[nt]);
          float* o = out + ob + (size_t)oc*16384 + gy*128 + gx;
          atomicAdd(o,       v); atomicAdd(o + 1,   v);
          atomicAdd(o + 128, v); atomicAdd(o + 129, v);
        }
      }
    }
  }
}

// ---------------- merged MoE kernel ----------------
// Per sample, blockIdx.x layout:
//   [0,384):     TYPE0, e = 3*(i/64),          tile = i%64   (8x8 tiles)
//   [384,1664):  TYPE1, e = 3*((i-384)/256)+1, tile = (i-384)%256 (16x16 tiles)
//   [1664,1744): TYPE2, e = 3*((i-1664)/16)+2, tile = (i-1664)%16 (4x4 tiles)
__global__ __launch_bounds__(256, 3) void moe_kernel(
    const unsigned short* __restrict__ xt, const unsigned short* __restrict__ wt,
    const float* __restrict__ wsf,
    const float* __restrict__ b1, const float* __restrict__ b2,
    float* __restrict__ out)
{
  __shared__ unsigned short xs[25600];   // 50 KB: input halo, then h1
  const int b = blockIdx.y;
  const int i = blockIdx.x;
  int e, tile, type;
  if (i < 384)       { type = 0; e = 3*(i>>6);            tile = i & 63;  }
  else if (i < 1664) { type = 1; e = 3*((i-384)>>8) + 1;  tile = (i-384) & 255; }
  else               { type = 2; e = 3*((i-1664)>>4) + 2; tile = (i-1664) & 15; }

  const float g = wsf[GATES_OFF_F + b*16 + e];
  if (g == 0.0f) return;                 // inactive expert for this sample

  if (type == 0)      expert_tile<0>(xt, wt, b1, b2, out, e, b, tile, g, xs);
  else if (type == 1) expert_tile<1>(xt, wt, b1, b2, out, e, b, tile, g, xs);
  else                expert_tile<2>(xt, wt, b1, b2, out, e, b, tile, g, xs);
}

extern "C" void kernel_launch(void* const* d_in, const int* in_sizes, int n_in,
                              void* d_out, int out_size, void* d_ws, size_t ws_size,
                              hipStream_t stream) {
  (void)in_sizes; (void)n_in; (void)ws_size;
  const float* x  = (const float*)d_in[0];
  const float* tf = (const float*)d_in[1];
  const float* Wx = (const float*)d_in[2];
  const float* Wt = (const float*)d_in[3];
  const float* bg = (const float*)d_in[4];
  const float* W1 = (const float*)d_in[5];
  const float* b1 = (const float*)d_in[6];
  const float* W2 = (const float*)d_in[7];
  const float* b2 = (const float*)d_in[8];
  float* out = (float*)d_out;
  unsigned short* wt = (unsigned short*)d_ws;
  float* wsf = (float*)d_ws;
  unsigned short* xtb = (unsigned short*)((char*)d_ws + XT_OFF_B);

  hipMemsetAsync(d_out, 0, (size_t)out_size*sizeof(float), stream);
  wtrans_kernel<<<4608, 256, 0, stream>>>(W1, W2, wt);
  xform_kernel<<<dim3(64, 16), 256, 0, stream>>>(x, xtb);
  pool_kernel<<<1024, 256, 0, stream>>>(x, wsf);
  gate_kernel<<<1, 256, 0, stream>>>(tf, Wx, Wt, bg, wsf, out + 16777216);

  moe_kernel<<<dim3(1744, 16), 256, 0, stream>>>(xtb, wt, wsf, b1, b2, out);
}

// Round 6
// 786.828 us; speedup vs baseline: 11.8266x; 1.0453x over previous
//
#include <hip/hip_runtime.h>
#include <cstdint>
#include <cstddef>

typedef __bf16 bf16x8 __attribute__((ext_vector_type(8)));
typedef float f32x4 __attribute__((ext_vector_type(4)));

// ---------------- ws layout ----------------
// bytes [0, 2359296): wt bf16 [16][2][9][64(oc)][64(ic)]
// float offset 589824: xp [16][64]; float offset 590848: gates [16][16]
// bytes [4MB, 4MB+33554432): xt bf16 [16][16384(pixel)][64(ch)]  (NHWC)
#define XP_OFF_F    589824
#define GATES_OFF_F 590848
#define XT_OFF_B    (4u<<20)

__device__ __forceinline__ float bf2f(unsigned short h){
  return __uint_as_float(((uint32_t)h)<<16);
}
__device__ __forceinline__ unsigned short f2bf(float f){
  uint32_t u = __float_as_uint(f);
  u = u + 0x7fffu + ((u>>16)&1u);   // RNE
  return (unsigned short)(u>>16);
}
__device__ __forceinline__ float gelu_exact(float x){
  return 0.5f*x*(1.0f + erff(x*0.70710678118654752440f));
}

// ---------------- weight transpose+cast: W[e][oc][ic][3][3] -> wt[e][c][tap][oc][ic] bf16
__global__ __launch_bounds__(256) void wtrans_kernel(const float* __restrict__ W1,
                                                     const float* __restrict__ W2,
                                                     unsigned short* __restrict__ wt){
  int idx = blockIdx.x*256 + threadIdx.x;      // 0 .. 1,179,647
  int ic  = idx & 63;
  int oc  = (idx>>6) & 63;
  int tap = (idx>>12) % 9;
  int ec  = idx / 36864;                       // e*2 + c
  int e = ec >> 1, c = ec & 1;
  const float* src = c ? W2 : W1;
  wt[idx] = f2bf(src[((e*64 + oc)*64 + ic)*9 + tap]);
}

// ---------------- x NCHW fp32 -> NHWC bf16
__global__ __launch_bounds__(256) void xform_kernel(const float* __restrict__ x,
                                                    unsigned short* __restrict__ xt){
  int b = blockIdx.y;
  int p = blockIdx.x*256 + threadIdx.x;        // 0..16383
  const float* xb = x + (size_t)b*1048576;
  unsigned short v[64];
  #pragma unroll
  for (int c = 0; c < 64; ++c)
    v[c] = f2bf(xb[c*16384 + p]);
  uint4* dst = reinterpret_cast<uint4*>(xt + (size_t)b*1048576 + (size_t)p*64);
  const uint4* src = reinterpret_cast<const uint4*>(v);
  #pragma unroll
  for (int i = 0; i < 8; ++i) dst[i] = src[i];
}

// ---------------- mean pool: xp[b][c] = mean_{h,w} x[b][c][h][w]
__global__ __launch_bounds__(256) void pool_kernel(const float* __restrict__ x,
                                                   float* __restrict__ wsf){
  int bc = blockIdx.x;                        // 0..1023
  const float* p = x + (size_t)bc*16384;
  int tid = threadIdx.x;
  float s = 0.f;
  for (int i = tid; i < 16384; i += 256) s += p[i];
  for (int off = 32; off; off >>= 1) s += __shfl_down(s, off);
  __shared__ float r[4];
  if ((tid & 63) == 0) r[tid>>6] = s;
  __syncthreads();
  if (tid == 0) wsf[XP_OFF_F + bc] = (r[0]+r[1]+r[2]+r[3]) * (1.0f/16384.0f);
}

// ---------------- gating: logits -> softmax -> top2 -> gates + aux
__global__ __launch_bounds__(256) void gate_kernel(const float* __restrict__ tf,
    const float* __restrict__ Wx, const float* __restrict__ Wt,
    const float* __restrict__ bg, float* __restrict__ wsf,
    float* __restrict__ out_aux){
  __shared__ float lg[16][16];
  __shared__ float gsh[16][16];
  int tid = threadIdx.x;
  int b = tid >> 4, e = tid & 15;
  const float* xp = wsf + XP_OFF_F;
  float acc = bg[e];
  for (int c = 0; c < 64;  ++c) acc += xp[b*64 + c] * Wx[c*16 + e];
  for (int d = 0; d < 512; ++d) acc += tf[b*512 + d] * Wt[d*16 + e];
  lg[b][e] = acc;
  __syncthreads();
  if (tid < 16) {
    int bb = tid;
    float m = -1e30f;
    for (int j = 0; j < 16; ++j) m = fmaxf(m, lg[bb][j]);
    float pr[16]; float s = 0.f;
    for (int j = 0; j < 16; ++j){ pr[j] = expf(lg[bb][j] - m); s += pr[j]; }
    float invs = 1.f/s;
    for (int j = 0; j < 16; ++j) pr[j] *= invs;
    int i1 = 0; float v1 = pr[0];
    for (int j = 1; j < 16; ++j) if (pr[j] > v1){ v1 = pr[j]; i1 = j; }
    float v2 = -1.f; int i2 = 0;
    for (int j = 0; j < 16; ++j) if (j != i1 && pr[j] > v2){ v2 = pr[j]; i2 = j; }
    float inv = 1.f/(v1 + v2);
    for (int j = 0; j < 16; ++j) gsh[bb][j] = 0.f;
    gsh[bb][i1] = v1*inv;
    gsh[bb][i2] = v2*inv;
    for (int j = 0; j < 16; ++j) wsf[GATES_OFF_F + bb*16 + j] = gsh[bb][j];
  }
  __syncthreads();
  if (tid == 0){
    float imp[16]; float mean = 0.f;
    for (int j = 0; j < 16; ++j){
      float t = 0.f;
      for (int bb = 0; bb < 16; ++bb) t += gsh[bb][j];
      imp[j] = t; mean += t;
    }
    mean *= (1.f/16.f);
    float m2 = 0.f;
    for (int j = 0; j < 16; ++j){ float d = imp[j] - mean; m2 += d*d; }
    float var = m2 * (1.f/16.f);
    out_aux[0] = var / (mean*mean + 1e-10f);
  }
}

// ---------------- merged MoE kernel (single instantiation; type is runtime) ----
// Per sample, blockIdx.x layout:
//   [0,384):     TYPE0, e = 3*(i/64),          tile = i%64   (8x8 tiles, S=128)
//   [384,1664):  TYPE1, e = 3*((i-384)/256)+1, tile = (i-384)%256 (16x16, S=256)
//   [1664,1744): TYPE2, e = 3*((i-1664)/16)+2, tile = (i-1664)%16 (4x4, S=64)
// conv as tap-decomposed GEMM on mfma_f32_16x16x32_bf16, software-pipelined:
// B-frags (global/L2) and A-frags (LDS) double-buffered across the 18-iter loop.
__global__ __launch_bounds__(256, 2) void moe_kernel(
    const unsigned short* __restrict__ xt, const unsigned short* __restrict__ wt,
    const float* __restrict__ wsf,
    const float* __restrict__ b1, const float* __restrict__ b2,
    float* __restrict__ out)
{
  __shared__ unsigned short xs[25600];   // 50 KB: input halo (20x20x64), then h1 (18x18x64)
  const int b = blockIdx.y;
  const int i = blockIdx.x;
  int e, tile, type, S, TILES;
  if (i < 384)       { type = 0; e = 3*(i>>6);            tile = i & 63;        S = 128; TILES = 8;  }
  else if (i < 1664) { type = 1; e = 3*((i-384)>>8) + 1;  tile = (i-384) & 255; S = 256; TILES = 16; }
  else               { type = 2; e = 3*((i-1664)>>4) + 2; tile = (i-1664) & 15; S = 64;  TILES = 4;  }

  const float g = wsf[GATES_OFF_F + b*16 + e];
  if (g == 0.0f) return;                 // inactive expert for this sample

  const int ty0 = (tile / TILES)*16;
  const int tx0 = (tile % TILES)*16;
  const int tid  = threadIdx.x;
  const int lane = tid & 63;
  const int wid  = tid >> 6;
  const int lr   = lane & 15;          // A-row / B-col index
  const int kg   = (lane >> 4) * 8;    // k-subgroup offset

  const unsigned short* wt1 = wt + (size_t)(e*2 + 0)*9*4096;
  const unsigned short* wt2 = wt + (size_t)(e*2 + 1)*9*4096;
  const unsigned short* xtb = xt + (size_t)b*1048576;   // [pixel][64]

  // ---- stage 20x20x64 input halo -> xs (bf16, swizzled)
  #pragma unroll
  for (int r = 0; r < 2; ++r){
    int p = r*256 + tid;
    if (p < 400){
      int hy = p/20, hx = p - hy*20;
      int sy = ty0 - 2 + hy, sx = tx0 - 2 + hx;      // conv-res coords
      bool valid = (sy >= 0) & (sy < S) & (sx >= 0) & (sx < S);
      int sw = (p & 7) * 8;
      if (!valid){
        uint4 z = make_uint4(0,0,0,0);
        #pragma unroll
        for (int icb = 0; icb < 8; ++icb)
          *reinterpret_cast<uint4*>(&xs[p*64 + ((icb*8) ^ sw)]) = z;
      } else if (type == 0){
        const uint4* src = reinterpret_cast<const uint4*>(xtb + ((size_t)(sy*128 + sx))*64);
        uint4 t[8];
        #pragma unroll
        for (int icb = 0; icb < 8; ++icb) t[icb] = src[icb];
        #pragma unroll
        for (int icb = 0; icb < 8; ++icb)
          *reinterpret_cast<uint4*>(&xs[p*64 + ((icb*8) ^ sw)]) = t[icb];
      } else if (type == 1){
        const uint4* src = reinterpret_cast<const uint4*>(xtb + ((size_t)((sy>>1)*128 + (sx>>1)))*64);
        uint4 t[8];
        #pragma unroll
        for (int icb = 0; icb < 8; ++icb) t[icb] = src[icb];
        #pragma unroll
        for (int icb = 0; icb < 8; ++icb)
          *reinterpret_cast<uint4*>(&xs[p*64 + ((icb*8) ^ sw)]) = t[icb];
      } else {
        // 2x2 maxpool on bf16 (exact: RNE is monotone)
        const uint4* q00 = reinterpret_cast<const uint4*>(xtb + ((size_t)(sy*256 + sx*2))*64);
        const uint4* q01 = q00 + 8;
        const uint4* q10 = q00 + 128*8;
        const uint4* q11 = q10 + 8;
        #pragma unroll
        for (int icb = 0; icb < 8; ++icb){
          union { unsigned short u[8]; uint4 v; } a0,a1,a2,a3,o;
          a0.v = q00[icb]; a1.v = q01[icb]; a2.v = q10[icb]; a3.v = q11[icb];
          #pragma unroll
          for (int j = 0; j < 8; ++j){
            float m = fmaxf(fmaxf(bf2f(a0.u[j]), bf2f(a1.u[j])),
                            fmaxf(bf2f(a2.u[j]), bf2f(a3.u[j])));
            o.u[j] = f2bf(m);
          }
          *reinterpret_cast<uint4*>(&xs[p*64 + ((icb*8) ^ sw)]) = o.v;
        }
      }
    }
  }

  // per-lane bias fragments
  float bias1v[4], bias2v[4];
  #pragma unroll
  for (int nt = 0; nt < 4; ++nt){
    bias1v[nt] = b1[e*64 + nt*16 + lr];
    bias2v[nt] = b2[e*64 + nt*16 + lr];
  }

  // conv1 m-fragment pixel bases (24 frags of 16 over 324 h1 pixels, clamped)
  int qb1[6];
  #pragma unroll
  for (int i2 = 0; i2 < 6; ++i2){
    int q = (wid*6 + i2)*16 + lr;
    q = q > 323 ? 323 : q;
    qb1[i2] = (q/18)*20 + (q%18);
  }

  // B-frag loader (weights, global/L2); A-frag loaders (LDS)
  bf16x8 Bb[2][4], Aa[2][6];
  auto load_b = [&](const unsigned short* wtx, int buf, int it){
    int tap = it >> 1, kf = it & 1;
    const unsigned short* wb = wtx + tap*4096 + lr*64 + (kf*32 + kg);
    #pragma unroll
    for (int nt = 0; nt < 4; ++nt)
      Bb[buf][nt] = *reinterpret_cast<const bf16x8*>(wb + nt*1024);
  };
  auto load_a1 = [&](int buf, int it){
    int tap = it >> 1, kf = it & 1;
    int poff = (tap/3)*20 + (tap%3);
    int icb = kf*32 + kg;
    #pragma unroll
    for (int ii = 0; ii < 6; ++ii){
      int p = qb1[ii] + poff;
      Aa[buf][ii] = *reinterpret_cast<const bf16x8*>(&xs[p*64 + (icb ^ ((p&7)*8))]);
    }
  };
  auto load_a2 = [&](int buf, int it){
    int tap = it >> 1, kf = it & 1;
    int dy = tap/3, dx = tap - dy*3;
    int icb = kf*32 + kg;
    #pragma unroll
    for (int ii = 0; ii < 4; ++ii){
      int p = (wid*4 + ii + dy)*18 + lr + dx;
      Aa[buf][ii] = *reinterpret_cast<const bf16x8*>(&xs[p*64 + (icb ^ ((p&7)*8))]);
    }
  };

  load_b(wt1, 0, 0);          // first weights in flight before the barrier
  __syncthreads();
  load_a1(0, 0);

  // ---- conv1: h1[324][64] = x (*) W1, pipelined 18-iteration MFMA loop
  f32x4 acc1[6][4];
  #pragma unroll
  for (int ii = 0; ii < 6; ++ii)
    #pragma unroll
    for (int nt = 0; nt < 4; ++nt)
      acc1[ii][nt] = (f32x4){0.f,0.f,0.f,0.f};

  #pragma unroll
  for (int it = 0; it < 18; ++it){
    const int cur = it & 1, nxt = cur ^ 1;
    if (it < 17){ load_b(wt1, nxt, it+1); load_a1(nxt, it+1); }
    #pragma unroll
    for (int ii = 0; ii < 6; ++ii)
      #pragma unroll
      for (int nt = 0; nt < 4; ++nt)
        acc1[ii][nt] = __builtin_amdgcn_mfma_f32_16x16x32_bf16(Aa[cur][ii], Bb[cur][nt], acc1[ii][nt], 0, 0, 0);
  }

  __syncthreads();   // all xs reads done; safe to overwrite with h1

  // ---- bias + GELU -> h1 (zero outside image: reference zero-pads h1)
  #pragma unroll
  for (int ii = 0; ii < 6; ++ii){
    int mf = wid*6 + ii;
    #pragma unroll
    for (int j = 0; j < 4; ++j){
      int q = mf*16 + (lane>>4)*4 + j;
      if (q < 324){
        int qy = q/18, qx = q - qy*18;
        int gy = ty0 - 1 + qy, gx = tx0 - 1 + qx;
        bool in_img = (gy >= 0) & (gy < S) & (gx >= 0) & (gx < S);
        int sw = (q & 7) * 8;
        #pragma unroll
        for (int nt = 0; nt < 4; ++nt){
          float v = in_img ? gelu_exact(acc1[ii][nt][j] + bias1v[nt]) : 0.f;
          xs[q*64 + ((nt*16 + lr) ^ sw)] = f2bf(v);
        }
      }
    }
  }

  load_b(wt2, 0, 0);          // conv2 first weights in flight before the barrier
  __syncthreads();
  load_a2(0, 0);

  // ---- conv2: out[256][64] = h1 (*) W2, pipelined
  f32x4 acc2[4][4];
  #pragma unroll
  for (int ii = 0; ii < 4; ++ii)
    #pragma unroll
    for (int nt = 0; nt < 4; ++nt)
      acc2[ii][nt] = (f32x4){0.f,0.f,0.f,0.f};

  #pragma unroll
  for (int it = 0; it < 18; ++it){
    const int cur = it & 1, nxt = cur ^ 1;
    if (it < 17){ load_b(wt2, nxt, it+1); load_a2(nxt, it+1); }
    #pragma unroll
    for (int ii = 0; ii < 4; ++ii)
      #pragma unroll
      for (int nt = 0; nt < 4; ++nt)
        acc2[ii][nt] = __builtin_amdgcn_mfma_f32_16x16x32_bf16(Aa[cur][ii], Bb[cur][nt], acc2[ii][nt], 0, 0, 0);
  }

  // ---- epilogue: bias + gate + resample + atomic accumulate
  // C/D layout: oc = nt*16 + lr; out-pixel py = wid*4 + ii, px = (lane>>4)*4 + j
  const size_t ob = (size_t)b*1048576;
  if (type == 0){
    #pragma unroll
    for (int ii = 0; ii < 4; ++ii){
      int py = wid*4 + ii;
      #pragma unroll
      for (int nt = 0; nt < 4; ++nt){
        int oc = nt*16 + lr;
        float* o = out + ob + (size_t)oc*16384 + (ty0+py)*128 + tx0;
        #pragma unroll
        for (int j = 0; j < 4; ++j){
          int px = (lane>>4)*4 + j;
          atomicAdd(o + px, g*(acc2[ii][nt][j] + bias2v[nt]));
        }
      }
    }
  } else if (type == 1){
    // 2x2 maxpool fully in-lane: px pairs = j pairs, py pairs = ii pairs
    #pragma unroll
    for (int i2 = 0; i2 < 2; ++i2){
      int Py = (ty0 + wid*4 + 2*i2) >> 1;
      #pragma unroll
      for (int nt = 0; nt < 4; ++nt){
        int oc = nt*16 + lr;
        float bb = bias2v[nt];
        #pragma unroll
        for (int j2 = 0; j2 < 2; ++j2){
          float m = fmaxf(fmaxf(acc2[2*i2][nt][2*j2],   acc2[2*i2][nt][2*j2+1]),
                          fmaxf(acc2[2*i2+1][nt][2*j2], acc2[2*i2+1][nt][2*j2+1]));
          int Px = (tx0 + (lane>>4)*4 + 2*j2) >> 1;
          atomicAdd(out + ob + (size_t)oc*16384 + Py*128 + Px, g*(m + bb));
        }
      }
    }
  } else {
    // nearest 2x upsample: each conv pixel -> 2x2 block at 128-res
    #pragma unroll
    for (int ii = 0; ii < 4; ++ii){
      int gy = (ty0 + wid*4 + ii)*2;
      #pragma unroll
      for (int nt = 0; nt < 4; ++nt){
        int oc = nt*16 + lr;
        #pragma unroll
        for (int j = 0; j < 4; ++j){
          int gx = (tx0 + (lane>>4)*4 + j)*2;
          float v = g*(acc2[ii][nt][j] + bias2v[nt]);
          float* o = out + ob + (size_t)oc*16384 + gy*128 + gx;
          atomicAdd(o,       v); atomicAdd(o + 1,   v);
          atomicAdd(o + 128, v); atomicAdd(o + 129, v);
        }
      }
    }
  }
}

extern "C" void kernel_launch(void* const* d_in, const int* in_sizes, int n_in,
                              void* d_out, int out_size, void* d_ws, size_t ws_size,
                              hipStream_t stream) {
  (void)in_sizes; (void)n_in; (void)ws_size;
  const float* x  = (const float*)d_in[0];
  const float* tf = (const float*)d_in[1];
  const float* Wx = (const float*)d_in[2];
  const float* Wt = (const float*)d_in[3];
  const float* bg = (const float*)d_in[4];
  const float* W1 = (const float*)d_in[5];
  const float* b1 = (const float*)d_in[6];
  const float* W2 = (const float*)d_in[7];
  const float* b2 = (const float*)d_in[8];
  float* out = (float*)d_out;
  unsigned short* wt = (unsigned short*)d_ws;
  float* wsf = (float*)d_ws;
  unsigned short* xtb = (unsigned short*)((char*)d_ws + XT_OFF_B);

  hipMemsetAsync(d_out, 0, (size_t)out_size*sizeof(float), stream);
  wtrans_kernel<<<4608, 256, 0, stream>>>(W1, W2, wt);
  xform_kernel<<<dim3(64, 16), 256, 0, stream>>>(x, xtb);
  pool_kernel<<<1024, 256, 0, stream>>>(x, wsf);
  gate_kernel<<<1, 256, 0, stream>>>(tf, Wx, Wt, bg, wsf, out + 16777216);

  moe_kernel<<<dim3(1744, 16), 256, 0, stream>>>(xtb, wt, wsf, b1, b2, out);
}

// Round 7
// 721.751 us; speedup vs baseline: 12.8929x; 1.0902x over previous
//
#include <hip/hip_runtime.h>
#include <cstdint>
#include <cstddef>

typedef __bf16 bf16x8 __attribute__((ext_vector_type(8)));
typedef float f32x4 __attribute__((ext_vector_type(4)));

// ---------------- ws layout ----------------
// bytes [0, 2359296): wt bf16 [16][2][9][64(oc)][64(ic)]
// float offset 589824: xp [16][64]; float offset 590848: gates [16][16]
// bytes [4MB, 4MB+33554432): xt bf16 [16][16384(pixel)][64(ch)]  (NHWC)
#define XP_OFF_F    589824
#define GATES_OFF_F 590848
#define XT_OFF_B    (4u<<20)

__device__ __forceinline__ float bf2f(unsigned short h){
  return __uint_as_float(((uint32_t)h)<<16);
}
__device__ __forceinline__ unsigned short f2bf(float f){
  uint32_t u = __float_as_uint(f);
  u = u + 0x7fffu + ((u>>16)&1u);   // RNE
  return (unsigned short)(u>>16);
}
// noinline: one erff body in .text instead of 48 inlined copies (I$)
__device__ __attribute__((noinline)) float gelu_exact(float x){
  return 0.5f*x*(1.0f + erff(x*0.70710678118654752440f));
}

// ---------------- weight transpose+cast: W[e][oc][ic][3][3] -> wt[e][c][tap][oc][ic] bf16
__global__ __launch_bounds__(256) void wtrans_kernel(const float* __restrict__ W1,
                                                     const float* __restrict__ W2,
                                                     unsigned short* __restrict__ wt){
  int idx = blockIdx.x*256 + threadIdx.x;      // 0 .. 1,179,647
  int ic  = idx & 63;
  int oc  = (idx>>6) & 63;
  int tap = (idx>>12) % 9;
  int ec  = idx / 36864;                       // e*2 + c
  int e = ec >> 1, c = ec & 1;
  const float* src = c ? W2 : W1;
  wt[idx] = f2bf(src[((e*64 + oc)*64 + ic)*9 + tap]);
}

// ---------------- x NCHW fp32 -> NHWC bf16
__global__ __launch_bounds__(256) void xform_kernel(const float* __restrict__ x,
                                                    unsigned short* __restrict__ xt){
  int b = blockIdx.y;
  int p = blockIdx.x*256 + threadIdx.x;        // 0..16383
  const float* xb = x + (size_t)b*1048576;
  unsigned short v[64];
  #pragma unroll
  for (int c = 0; c < 64; ++c)
    v[c] = f2bf(xb[c*16384 + p]);
  uint4* dst = reinterpret_cast<uint4*>(xt + (size_t)b*1048576 + (size_t)p*64);
  const uint4* src = reinterpret_cast<const uint4*>(v);
  #pragma unroll
  for (int i = 0; i < 8; ++i) dst[i] = src[i];
}

// ---------------- mean pool: xp[b][c] = mean_{h,w} x[b][c][h][w]
__global__ __launch_bounds__(256) void pool_kernel(const float* __restrict__ x,
                                                   float* __restrict__ wsf){
  int bc = blockIdx.x;                        // 0..1023
  const float* p = x + (size_t)bc*16384;
  int tid = threadIdx.x;
  float s = 0.f;
  for (int i = tid; i < 16384; i += 256) s += p[i];
  for (int off = 32; off; off >>= 1) s += __shfl_down(s, off);
  __shared__ float r[4];
  if ((tid & 63) == 0) r[tid>>6] = s;
  __syncthreads();
  if (tid == 0) wsf[XP_OFF_F + bc] = (r[0]+r[1]+r[2]+r[3]) * (1.0f/16384.0f);
}

// ---------------- gating: logits -> softmax -> top2 -> gates + aux
__global__ __launch_bounds__(256) void gate_kernel(const float* __restrict__ tf,
    const float* __restrict__ Wx, const float* __restrict__ Wt,
    const float* __restrict__ bg, float* __restrict__ wsf,
    float* __restrict__ out_aux){
  __shared__ float lg[16][16];
  __shared__ float gsh[16][16];
  int tid = threadIdx.x;
  int b = tid >> 4, e = tid & 15;
  const float* xp = wsf + XP_OFF_F;
  float acc = bg[e];
  for (int c = 0; c < 64;  ++c) acc += xp[b*64 + c] * Wx[c*16 + e];
  for (int d = 0; d < 512; ++d) acc += tf[b*512 + d] * Wt[d*16 + e];
  lg[b][e] = acc;
  __syncthreads();
  if (tid < 16) {
    int bb = tid;
    float m = -1e30f;
    for (int j = 0; j < 16; ++j) m = fmaxf(m, lg[bb][j]);
    float pr[16]; float s = 0.f;
    for (int j = 0; j < 16; ++j){ pr[j] = expf(lg[bb][j] - m); s += pr[j]; }
    float invs = 1.f/s;
    for (int j = 0; j < 16; ++j) pr[j] *= invs;
    int i1 = 0; float v1 = pr[0];
    for (int j = 1; j < 16; ++j) if (pr[j] > v1){ v1 = pr[j]; i1 = j; }
    float v2 = -1.f; int i2 = 0;
    for (int j = 0; j < 16; ++j) if (j != i1 && pr[j] > v2){ v2 = pr[j]; i2 = j; }
    float inv = 1.f/(v1 + v2);
    for (int j = 0; j < 16; ++j) gsh[bb][j] = 0.f;
    gsh[bb][i1] = v1*inv;
    gsh[bb][i2] = v2*inv;
    for (int j = 0; j < 16; ++j) wsf[GATES_OFF_F + bb*16 + j] = gsh[bb][j];
  }
  __syncthreads();
  if (tid == 0){
    float imp[16]; float mean = 0.f;
    for (int j = 0; j < 16; ++j){
      float t = 0.f;
      for (int bb = 0; bb < 16; ++bb) t += gsh[bb][j];
      imp[j] = t; mean += t;
    }
    mean *= (1.f/16.f);
    float m2 = 0.f;
    for (int j = 0; j < 16; ++j){ float d = imp[j] - mean; m2 += d*d; }
    float var = m2 * (1.f/16.f);
    out_aux[0] = var / (mean*mean + 1e-10f);
  }
}

// ---------------- merged MoE kernel: 512 threads (8 waves), swapped-operand MFMA
// Per sample, blockIdx.x layout:
//   [0,384):     TYPE0, e = 3*(i/64),          tile = i%64   (8x8 tiles, S=128)
//   [384,1664):  TYPE1, e = 3*((i-384)/256)+1, tile = (i-384)%256 (16x16, S=256)
//   [1664,1744): TYPE2, e = 3*((i-1664)/16)+2, tile = (i-1664)%16 (4x4, S=64)
// conv as tap-decomposed GEMM: D[oc][px] = mfma(A=W[oc][ic], B=P[px][ic]).
// C-layout: px = lane&15 (consecutive -> line-coalesced epilogue), oc = (lane>>4)*4+reg.
__global__ __launch_bounds__(512, 4) void moe_kernel(
    const unsigned short* __restrict__ xt, const unsigned short* __restrict__ wt,
    const float* __restrict__ wsf,
    const float* __restrict__ b1, const float* __restrict__ b2,
    float* __restrict__ out)
{
  __shared__ unsigned short xs[25600];   // 50 KB: input halo (20x20x64), then h1 (18x18x64)
  const int b = blockIdx.y;
  const int i = blockIdx.x;
  int e, tile, type, S, TILES;
  if (i < 384)       { type = 0; e = 3*(i>>6);            tile = i & 63;        S = 128; TILES = 8;  }
  else if (i < 1664) { type = 1; e = 3*((i-384)>>8) + 1;  tile = (i-384) & 255; S = 256; TILES = 16; }
  else               { type = 2; e = 3*((i-1664)>>4) + 2; tile = (i-1664) & 15; S = 64;  TILES = 4;  }

  const float g = wsf[GATES_OFF_F + b*16 + e];
  if (g == 0.0f) return;                 // inactive expert for this sample

  const int ty0 = (tile / TILES)*16;
  const int tx0 = (tile % TILES)*16;
  const int tid  = threadIdx.x;
  const int lane = tid & 63;
  const int wid  = tid >> 6;           // 0..7
  const int lr   = lane & 15;          // A-row(oc) for W-frags / B-col(px) for P-frags
  const int kg   = (lane >> 4) * 8;    // k-subgroup offset
  const int l4   = (lane >> 4) * 4;    // C/D row sub-offset

  const unsigned short* wt1 = wt + (size_t)(e*2 + 0)*36864;
  const unsigned short* wt2 = wt + (size_t)(e*2 + 1)*36864;
  const unsigned short* xtb = xt + (size_t)b*1048576;   // [pixel][64]

  // ---- stage 20x20x64 input halo -> xs (bf16, swizzled); 400 px, 1 per thread
  if (tid < 400){
    int p = tid;
    int hy = p/20, hx = p - hy*20;
    int sy = ty0 - 2 + hy, sx = tx0 - 2 + hx;      // conv-res coords
    bool valid = (sy >= 0) & (sy < S) & (sx < S) & (sx >= 0);
    int sw = (p & 7) * 8;
    if (!valid){
      uint4 z = make_uint4(0,0,0,0);
      #pragma unroll
      for (int icb = 0; icb < 8; ++icb)
        *reinterpret_cast<uint4*>(&xs[p*64 + ((icb*8) ^ sw)]) = z;
    } else if (type == 0){
      const uint4* src = reinterpret_cast<const uint4*>(xtb + ((size_t)(sy*128 + sx))*64);
      #pragma unroll
      for (int icb = 0; icb < 8; ++icb)
        *reinterpret_cast<uint4*>(&xs[p*64 + ((icb*8) ^ sw)]) = src[icb];
    } else if (type == 1){
      const uint4* src = reinterpret_cast<const uint4*>(xtb + ((size_t)((sy>>1)*128 + (sx>>1)))*64);
      #pragma unroll
      for (int icb = 0; icb < 8; ++icb)
        *reinterpret_cast<uint4*>(&xs[p*64 + ((icb*8) ^ sw)]) = src[icb];
    } else {
      // 2x2 maxpool on bf16 (exact: RNE is monotone)
      const uint4* q00 = reinterpret_cast<const uint4*>(xtb + ((size_t)(sy*256 + sx*2))*64);
      const uint4* q01 = q00 + 8;
      const uint4* q10 = q00 + 128*8;
      const uint4* q11 = q10 + 8;
      #pragma unroll
      for (int icb = 0; icb < 8; ++icb){
        union { unsigned short u[8]; uint4 v; } a0,a1,a2,a3,o;
        a0.v = q00[icb]; a1.v = q01[icb]; a2.v = q10[icb]; a3.v = q11[icb];
        #pragma unroll
        for (int j = 0; j < 8; ++j){
          float m = fmaxf(fmaxf(bf2f(a0.u[j]), bf2f(a1.u[j])),
                          fmaxf(bf2f(a2.u[j]), bf2f(a3.u[j])));
          o.u[j] = f2bf(m);
        }
        *reinterpret_cast<uint4*>(&xs[p*64 + ((icb*8) ^ sw)]) = o.v;
      }
    }
  }

  // conv1 m... B-frag pixel bases: 24 frags of 16 over 324 h1 pixels (clamped)
  int qb1[3];
  #pragma unroll
  for (int ii = 0; ii < 3; ++ii){
    int q = (wid*3 + ii)*16 + lr;
    q = q > 323 ? 323 : q;
    qb1[ii] = (q/18)*20 + (q%18);
  }

  __syncthreads();

  // ---- conv1: h1 = x (*) W1 ; D[oc][q], per wave 3 px-frags x 4 oc-frags
  f32x4 acc1[3][4];
  #pragma unroll
  for (int ii = 0; ii < 3; ++ii)
    #pragma unroll
    for (int nt = 0; nt < 4; ++nt)
      acc1[ii][nt] = (f32x4){0.f,0.f,0.f,0.f};

  #pragma unroll 2
  for (int it = 0; it < 18; ++it){
    int tap = it >> 1, kf = it & 1;
    int icb = kf*32 + kg;
    const unsigned short* wb = wt1 + tap*4096 + lr*64 + icb;
    bf16x8 Wf[4];
    #pragma unroll
    for (int nt = 0; nt < 4; ++nt)
      Wf[nt] = *reinterpret_cast<const bf16x8*>(wb + nt*1024);
    int t3 = tap/3;
    int poff = t3*20 + (tap - t3*3);
    bf16x8 Pf[3];
    #pragma unroll
    for (int ii = 0; ii < 3; ++ii){
      int p = qb1[ii] + poff;
      Pf[ii] = *reinterpret_cast<const bf16x8*>(&xs[p*64 + (icb ^ ((p&7)*8))]);
    }
    #pragma unroll
    for (int ii = 0; ii < 3; ++ii)
      #pragma unroll
      for (int nt = 0; nt < 4; ++nt)
        acc1[ii][nt] = __builtin_amdgcn_mfma_f32_16x16x32_bf16(Wf[nt], Pf[ii], acc1[ii][nt], 0, 0, 0);
  }

  __syncthreads();   // all xs reads done; safe to overwrite with h1

  // ---- bias + GELU -> h1 (zero outside image: reference zero-pads h1)
  #pragma unroll
  for (int ii = 0; ii < 3; ++ii){
    int q = (wid*3 + ii)*16 + lr;
    if (q < 324){
      int qy = q/18, qx = q - qy*18;
      int gy = ty0 - 1 + qy, gx = tx0 - 1 + qx;
      bool in_img = (gy >= 0) & (gy < S) & (gx >= 0) & (gx < S);
      int sw = (q & 7) * 8;
      #pragma unroll
      for (int nt = 0; nt < 4; ++nt)
        #pragma unroll
        for (int j = 0; j < 4; ++j){
          int oc = nt*16 + l4 + j;
          float v = in_img ? gelu_exact(acc1[ii][nt][j] + b1[e*64 + oc]) : 0.f;
          xs[q*64 + (oc ^ sw)] = f2bf(v);
        }
    }
  }

  __syncthreads();

  // ---- conv2: out = h1 (*) W2 ; D[oc][px], per wave 2 px-frags (rows wid*2, wid*2+1)
  f32x4 acc2[2][4];
  #pragma unroll
  for (int ii = 0; ii < 2; ++ii)
    #pragma unroll
    for (int nt = 0; nt < 4; ++nt)
      acc2[ii][nt] = (f32x4){0.f,0.f,0.f,0.f};

  #pragma unroll 2
  for (int it = 0; it < 18; ++it){
    int tap = it >> 1, kf = it & 1;
    int icb = kf*32 + kg;
    const unsigned short* wb = wt2 + tap*4096 + lr*64 + icb;
    bf16x8 Wf[4];
    #pragma unroll
    for (int nt = 0; nt < 4; ++nt)
      Wf[nt] = *reinterpret_cast<const bf16x8*>(wb + nt*1024);
    int t3 = tap/3;
    int dy = t3, dx = tap - t3*3;
    bf16x8 Pf[2];
    #pragma unroll
    for (int ii = 0; ii < 2; ++ii){
      int p = (wid*2 + ii + dy)*18 + lr + dx;
      Pf[ii] = *reinterpret_cast<const bf16x8*>(&xs[p*64 + (icb ^ ((p&7)*8))]);
    }
    #pragma unroll
    for (int ii = 0; ii < 2; ++ii)
      #pragma unroll
      for (int nt = 0; nt < 4; ++nt)
        acc2[ii][nt] = __builtin_amdgcn_mfma_f32_16x16x32_bf16(Wf[nt], Pf[ii], acc2[ii][nt], 0, 0, 0);
  }

  // ---- epilogue: bias + gate + resample + line-coalesced atomic accumulate
  // lane holds px = lr (16 consecutive), oc = nt*16 + l4 + j, conv row py = wid*2 + ii
  const size_t ob = (size_t)b*1048576;
  if (type == 0){
    #pragma unroll
    for (int ii = 0; ii < 2; ++ii){
      int gy = ty0 + wid*2 + ii;
      #pragma unroll
      for (int nt = 0; nt < 4; ++nt)
        #pragma unroll
        for (int j = 0; j < 4; ++j){
          int oc = nt*16 + l4 + j;
          atomicAdd(out + ob + (size_t)oc*16384 + gy*128 + tx0 + lr,
                    g*(acc2[ii][nt][j] + b2[e*64 + oc]));
        }
    }
  } else if (type == 1){
    // 2x2 maxpool: vertical pair in-register (ii 0/1), horizontal pair cross-lane
    int Py = (ty0 + wid*2) >> 1;
    int Px = (tx0 + lr) >> 1;
    #pragma unroll
    for (int nt = 0; nt < 4; ++nt)
      #pragma unroll
      for (int j = 0; j < 4; ++j){
        int oc = nt*16 + l4 + j;
        float v = fmaxf(acc2[0][nt][j], acc2[1][nt][j]);
        v = fmaxf(v, __shfl_xor(v, 1));
        if ((lane & 1) == 0)
          atomicAdd(out + ob + (size_t)oc*16384 + Py*128 + Px, g*(v + b2[e*64 + oc]));
      }
  } else {
    // nearest 2x upsample: each conv pixel -> 2x2 block at 128-res
    #pragma unroll
    for (int ii = 0; ii < 2; ++ii){
      int gy = (ty0 + wid*2 + ii)*2;
      #pragma unroll
      for (int nt = 0; nt < 4; ++nt)
        #pragma unroll
        for (int j = 0; j < 4; ++j){
          int oc = nt*16 + l4 + j;
          float v = g*(acc2[ii][nt][j] + b2[e*64 + oc]);
          float* o = out + ob + (size_t)oc*16384 + gy*128 + (tx0 + lr)*2;
          atomicAdd(o,       v); atomicAdd(o + 1,   v);
          atomicAdd(o + 128, v); atomicAdd(o + 129, v);
        }
    }
  }
}

extern "C" void kernel_launch(void* const* d_in, const int* in_sizes, int n_in,
                              void* d_out, int out_size, void* d_ws, size_t ws_size,
                              hipStream_t stream) {
  (void)in_sizes; (void)n_in; (void)ws_size;
  const float* x  = (const float*)d_in[0];
  const float* tf = (const float*)d_in[1];
  const float* Wx = (const float*)d_in[2];
  const float* Wt = (const float*)d_in[3];
  const float* bg = (const float*)d_in[4];
  const float* W1 = (const float*)d_in[5];
  const float* b1 = (const float*)d_in[6];
  const float* W2 = (const float*)d_in[7];
  const float* b2 = (const float*)d_in[8];
  float* out = (float*)d_out;
  unsigned short* wt = (unsigned short*)d_ws;
  float* wsf = (float*)d_ws;
  unsigned short* xtb = (unsigned short*)((char*)d_ws + XT_OFF_B);

  hipMemsetAsync(d_out, 0, (size_t)out_size*sizeof(float), stream);
  wtrans_kernel<<<4608, 256, 0, stream>>>(W1, W2, wt);
  xform_kernel<<<dim3(64, 16), 256, 0, stream>>>(x, xtb);
  pool_kernel<<<1024, 256, 0, stream>>>(x, wsf);
  gate_kernel<<<1, 256, 0, stream>>>(tf, Wx, Wt, bg, wsf, out + 16777216);

  moe_kernel<<<dim3(1744, 16), 512, 0, stream>>>(xtb, wt, wsf, b1, b2, out);
}

// Round 8
// 409.523 us; speedup vs baseline: 22.7228x; 1.7624x over previous
//
#include <hip/hip_runtime.h>
#include <cstdint>
#include <cstddef>

typedef __bf16 bf16x8 __attribute__((ext_vector_type(8)));
typedef float f32x4 __attribute__((ext_vector_type(4)));

// ---------------- ws layout ----------------
// bytes [0, 2359296): wt bf16 [16][2][9][64(oc)][64(ic)]
// float offset 589824: xp [16][64]; float offset 590848: gates [16][16]
// bytes [4MB, 4MB+33554432): xt bf16 [16][16384(pixel)][64(ch)]  (NHWC)
#define XP_OFF_F    589824
#define GATES_OFF_F 590848
#define XT_OFF_B    (4u<<20)

__device__ __forceinline__ float bf2f(unsigned short h){
  return __uint_as_float(((uint32_t)h)<<16);
}
__device__ __forceinline__ unsigned short f2bf(float f){
  uint32_t u = __float_as_uint(f);
  u = u + 0x7fffu + ((u>>16)&1u);   // RNE
  return (unsigned short)(u>>16);
}
// noinline: one erff body in .text instead of 48 inlined copies (I$)
__device__ __attribute__((noinline)) float gelu_exact(float x){
  return 0.5f*x*(1.0f + erff(x*0.70710678118654752440f));
}

// ---------------- weight transpose+cast: W[e][oc][ic][3][3] -> wt[e][c][tap][oc][ic] bf16
__global__ __launch_bounds__(256) void wtrans_kernel(const float* __restrict__ W1,
                                                     const float* __restrict__ W2,
                                                     unsigned short* __restrict__ wt){
  int idx = blockIdx.x*256 + threadIdx.x;      // 0 .. 1,179,647
  int ic  = idx & 63;
  int oc  = (idx>>6) & 63;
  int tap = (idx>>12) % 9;
  int ec  = idx / 36864;                       // e*2 + c
  int e = ec >> 1, c = ec & 1;
  const float* src = c ? W2 : W1;
  wt[idx] = f2bf(src[((e*64 + oc)*64 + ic)*9 + tap]);
}

// ---------------- x NCHW fp32 -> NHWC bf16
__global__ __launch_bounds__(256) void xform_kernel(const float* __restrict__ x,
                                                    unsigned short* __restrict__ xt){
  int b = blockIdx.y;
  int p = blockIdx.x*256 + threadIdx.x;        // 0..16383
  const float* xb = x + (size_t)b*1048576;
  unsigned short v[64];
  #pragma unroll
  for (int c = 0; c < 64; ++c)
    v[c] = f2bf(xb[c*16384 + p]);
  uint4* dst = reinterpret_cast<uint4*>(xt + (size_t)b*1048576 + (size_t)p*64);
  const uint4* src = reinterpret_cast<const uint4*>(v);
  #pragma unroll
  for (int i = 0; i < 8; ++i) dst[i] = src[i];
}

// ---------------- mean pool: xp[b][c] = mean_{h,w} x[b][c][h][w]
__global__ __launch_bounds__(256) void pool_kernel(const float* __restrict__ x,
                                                   float* __restrict__ wsf){
  int bc = blockIdx.x;                        // 0..1023
  const float* p = x + (size_t)bc*16384;
  int tid = threadIdx.x;
  float s = 0.f;
  for (int i = tid; i < 16384; i += 256) s += p[i];
  for (int off = 32; off; off >>= 1) s += __shfl_down(s, off);
  __shared__ float r[4];
  if ((tid & 63) == 0) r[tid>>6] = s;
  __syncthreads();
  if (tid == 0) wsf[XP_OFF_F + bc] = (r[0]+r[1]+r[2]+r[3]) * (1.0f/16384.0f);
}

// ---------------- gating: logits -> softmax -> top2 -> gates + aux
__global__ __launch_bounds__(256) void gate_kernel(const float* __restrict__ tf,
    const float* __restrict__ Wx, const float* __restrict__ Wt,
    const float* __restrict__ bg, float* __restrict__ wsf,
    float* __restrict__ out_aux){
  __shared__ float lg[16][16];
  __shared__ float gsh[16][16];
  int tid = threadIdx.x;
  int b = tid >> 4, e = tid & 15;
  const float* xp = wsf + XP_OFF_F;
  float acc = bg[e];
  for (int c = 0; c < 64;  ++c) acc += xp[b*64 + c] * Wx[c*16 + e];
  for (int d = 0; d < 512; ++d) acc += tf[b*512 + d] * Wt[d*16 + e];
  lg[b][e] = acc;
  __syncthreads();
  if (tid < 16) {
    int bb = tid;
    float m = -1e30f;
    for (int j = 0; j < 16; ++j) m = fmaxf(m, lg[bb][j]);
    float pr[16]; float s = 0.f;
    for (int j = 0; j < 16; ++j){ pr[j] = expf(lg[bb][j] - m); s += pr[j]; }
    float invs = 1.f/s;
    for (int j = 0; j < 16; ++j) pr[j] *= invs;
    int i1 = 0; float v1 = pr[0];
    for (int j = 1; j < 16; ++j) if (pr[j] > v1){ v1 = pr[j]; i1 = j; }
    float v2 = -1.f; int i2 = 0;
    for (int j = 0; j < 16; ++j) if (j != i1 && pr[j] > v2){ v2 = pr[j]; i2 = j; }
    float inv = 1.f/(v1 + v2);
    for (int j = 0; j < 16; ++j) gsh[bb][j] = 0.f;
    gsh[bb][i1] = v1*inv;
    gsh[bb][i2] = v2*inv;
    for (int j = 0; j < 16; ++j) wsf[GATES_OFF_F + bb*16 + j] = gsh[bb][j];
  }
  __syncthreads();
  if (tid == 0){
    float imp[16]; float mean = 0.f;
    for (int j = 0; j < 16; ++j){
      float t = 0.f;
      for (int bb = 0; bb < 16; ++bb) t += gsh[bb][j];
      imp[j] = t; mean += t;
    }
    mean *= (1.f/16.f);
    float m2 = 0.f;
    for (int j = 0; j < 16; ++j){ float d = imp[j] - mean; m2 += d*d; }
    float var = m2 * (1.f/16.f);
    out_aux[0] = var / (mean*mean + 1e-10f);
  }
}

// ---------------- merged MoE kernel: 512 threads, swapped-operand MFMA,
// weights LDS-staged through a 3-deep double buffer (reg-staged, T14 split).
// Per sample, blockIdx.x layout:
//   [0,384):     TYPE0, e = 3*(i/64),          tile = i%64   (8x8 tiles, S=128)
//   [384,1664):  TYPE1, e = 3*((i-384)/256)+1, tile = (i-384)%256 (16x16, S=256)
//   [1664,1744): TYPE2, e = 3*((i-1664)/16)+2, tile = (i-1664)%16 (4x4, S=64)
// conv as tap-decomposed GEMM: D[oc][px] = mfma(A=W[oc][ic], B=P[px][ic]).
__global__ __launch_bounds__(512, 4) void moe_kernel(
    const unsigned short* __restrict__ xt, const unsigned short* __restrict__ wt,
    const float* __restrict__ wsf,
    const float* __restrict__ b1, const float* __restrict__ b2,
    float* __restrict__ out)
{
  __shared__ unsigned short xs[25600];     // 50 KB: input halo (20x20x64), then h1
  __shared__ unsigned short wbuf[3][2048]; // 12 KB: 3 x [64oc][32ic] weight slabs
  const int b = blockIdx.y;
  const int i = blockIdx.x;
  int e, tile, type, S, TILES;
  if (i < 384)       { type = 0; e = 3*(i>>6);            tile = i & 63;        S = 128; TILES = 8;  }
  else if (i < 1664) { type = 1; e = 3*((i-384)>>8) + 1;  tile = (i-384) & 255; S = 256; TILES = 16; }
  else               { type = 2; e = 3*((i-1664)>>4) + 2; tile = (i-1664) & 15; S = 64;  TILES = 4;  }

  const float g = wsf[GATES_OFF_F + b*16 + e];
  if (g == 0.0f) return;                 // inactive expert for this sample

  const int ty0 = (tile / TILES)*16;
  const int tx0 = (tile % TILES)*16;
  const int tid  = threadIdx.x;
  const int lane = tid & 63;
  const int wid  = tid >> 6;           // 0..7
  const int lr   = lane & 15;
  const int k16  = lane >> 4;          // 0..3
  const int kg   = k16 * 8;            // k-subgroup offset
  const int l4   = k16 * 4;            // C/D row sub-offset

  const unsigned short* wt1 = wt + (size_t)(e*2 + 0)*36864;
  const unsigned short* wt2 = wt + (size_t)(e*2 + 1)*36864;
  const unsigned short* xtb = xt + (size_t)b*1048576;   // [pixel][64]

  // weight staging helpers (threads 0..255 stage; 1 uint4 each per iteration)
  // global slab j (0..35): conv = j>=18, jj = j%18, tap = jj>>1, kf = jj&1.
  // LDS layout linear: thread t -> byte t*16 (row oc=t>>2, chunk ch=t&3).
  // Source chunk = ch ^ ((oc>>1)&3)  (inverse swizzle; reader XORs the same).
  const int woc = tid >> 2, wch = tid & 3;
  const int wsc = wch ^ ((woc >> 1) & 3);
  const int wdst = woc*32 + wch*8;                    // ushort offset = t*8
  auto wsrc = [&](int j)->const uint4*{
    int conv = j >= 18; int jj = j - (conv ? 18 : 0);
    int tap = jj >> 1, kf = jj & 1;
    return reinterpret_cast<const uint4*>(
      (conv ? wt2 : wt1) + tap*4096 + woc*64 + kf*32 + wsc*8);
  };
  // reader swizzle: Wf[nt] at wbuf[cur][ (nt*16+lr)*32 + (k16 ^ ((lr>>1)&3))*8 ]
  const int lrw = lr*32 + ((k16 ^ ((lr>>1)&3))*8);

  // ---- stage 20x20x64 input halo -> xs (bf16, swizzled); 400 px, 1 per thread
  if (tid < 400){
    int p = tid;
    int hy = p/20, hx = p - hy*20;
    int sy = ty0 - 2 + hy, sx = tx0 - 2 + hx;      // conv-res coords
    bool valid = (sy >= 0) & (sy < S) & (sx < S) & (sx >= 0);
    int sw = (p & 7) * 8;
    if (!valid){
      uint4 z = make_uint4(0,0,0,0);
      #pragma unroll
      for (int icb = 0; icb < 8; ++icb)
        *reinterpret_cast<uint4*>(&xs[p*64 + ((icb*8) ^ sw)]) = z;
    } else if (type == 0){
      const uint4* src = reinterpret_cast<const uint4*>(xtb + ((size_t)(sy*128 + sx))*64);
      #pragma unroll
      for (int icb = 0; icb < 8; ++icb)
        *reinterpret_cast<uint4*>(&xs[p*64 + ((icb*8) ^ sw)]) = src[icb];
    } else if (type == 1){
      const uint4* src = reinterpret_cast<const uint4*>(xtb + ((size_t)((sy>>1)*128 + (sx>>1)))*64);
      #pragma unroll
      for (int icb = 0; icb < 8; ++icb)
        *reinterpret_cast<uint4*>(&xs[p*64 + ((icb*8) ^ sw)]) = src[icb];
    } else {
      // 2x2 maxpool on bf16 (exact: RNE is monotone)
      const uint4* q00 = reinterpret_cast<const uint4*>(xtb + ((size_t)(sy*256 + sx*2))*64);
      const uint4* q01 = q00 + 8;
      const uint4* q10 = q00 + 128*8;
      const uint4* q11 = q10 + 8;
      #pragma unroll
      for (int icb = 0; icb < 8; ++icb){
        union { unsigned short u[8]; uint4 v; } a0,a1,a2,a3,o;
        a0.v = q00[icb]; a1.v = q01[icb]; a2.v = q10[icb]; a3.v = q11[icb];
        #pragma unroll
        for (int j = 0; j < 8; ++j){
          float m = fmaxf(fmaxf(bf2f(a0.u[j]), bf2f(a1.u[j])),
                          fmaxf(bf2f(a2.u[j]), bf2f(a3.u[j])));
          o.u[j] = f2bf(m);
        }
        *reinterpret_cast<uint4*>(&xs[p*64 + ((icb*8) ^ sw)]) = o.v;
      }
    }
  }

  // ---- weight pipeline prologue: slabs 0,1 direct to LDS; slab 2 into regs
  uint4 wreg;
  if (tid < 256){
    uint4 w0 = *wsrc(0);
    uint4 w1 = *wsrc(1);
    *reinterpret_cast<uint4*>(&wbuf[0][wdst]) = w0;
    *reinterpret_cast<uint4*>(&wbuf[1][wdst]) = w1;
    wreg = *wsrc(2);
  }

  // conv1 B-frag pixel bases: 24 frags of 16 over 324 h1 pixels (clamped)
  int qb1[3];
  #pragma unroll
  for (int ii = 0; ii < 3; ++ii){
    int q = (wid*3 + ii)*16 + lr;
    q = q > 323 ? 323 : q;
    qb1[ii] = (q/18)*20 + (q%18);
  }

  asm volatile("s_waitcnt lgkmcnt(0)" ::: "memory");
  __builtin_amdgcn_s_barrier();

  // ---- conv1: 18 iterations, weights from LDS, 3-deep pipeline
  f32x4 acc1[3][4];
  #pragma unroll
  for (int ii = 0; ii < 3; ++ii)
    #pragma unroll
    for (int nt = 0; nt < 4; ++nt)
      acc1[ii][nt] = (f32x4){0.f,0.f,0.f,0.f};

  for (int it = 0; it < 18; ++it){
    const unsigned short* wb = &wbuf[it % 3][0];
    if (tid < 256){
      *reinterpret_cast<uint4*>(&wbuf[(it+2) % 3][wdst]) = wreg;  // slab it+2
      wreg = *wsrc(it+3);                                         // slab it+3
    }
    int tap = it >> 1, kf = it & 1;
    int icb = kf*32 + kg;
    bf16x8 Wf[4];
    #pragma unroll
    for (int nt = 0; nt < 4; ++nt)
      Wf[nt] = *reinterpret_cast<const bf16x8*>(wb + nt*512 + lrw);
    int t3 = tap/3;
    int poff = t3*20 + (tap - t3*3);
    bf16x8 Pf[3];
    #pragma unroll
    for (int ii = 0; ii < 3; ++ii){
      int p = qb1[ii] + poff;
      Pf[ii] = *reinterpret_cast<const bf16x8*>(&xs[p*64 + (icb ^ ((p&7)*8))]);
    }
    #pragma unroll
    for (int ii = 0; ii < 3; ++ii)
      #pragma unroll
      for (int nt = 0; nt < 4; ++nt)
        acc1[ii][nt] = __builtin_amdgcn_mfma_f32_16x16x32_bf16(Wf[nt], Pf[ii], acc1[ii][nt], 0, 0, 0);
    asm volatile("s_waitcnt lgkmcnt(0)" ::: "memory");
    __builtin_amdgcn_s_barrier();
  }

  // ---- bias + GELU -> h1 (zero outside image: reference zero-pads h1)
  #pragma unroll
  for (int ii = 0; ii < 3; ++ii){
    int q = (wid*3 + ii)*16 + lr;
    if (q < 324){
      int qy = q/18, qx = q - qy*18;
      int gy = ty0 - 1 + qy, gx = tx0 - 1 + qx;
      bool in_img = (gy >= 0) & (gy < S) & (gx >= 0) & (gx < S);
      int sw = (q & 7) * 8;
      #pragma unroll
      for (int nt = 0; nt < 4; ++nt)
        #pragma unroll
        for (int j = 0; j < 4; ++j){
          int oc = nt*16 + l4 + j;
          float v = in_img ? gelu_exact(acc1[ii][nt][j] + b1[e*64 + oc]) : 0.f;
          xs[q*64 + (oc ^ sw)] = f2bf(v);
        }
    }
  }

  asm volatile("s_waitcnt lgkmcnt(0)" ::: "memory");
  __builtin_amdgcn_s_barrier();

  // ---- conv2: 18 iterations (global slabs 18..35), same pipeline
  f32x4 acc2[2][4];
  #pragma unroll
  for (int ii = 0; ii < 2; ++ii)
    #pragma unroll
    for (int nt = 0; nt < 4; ++nt)
      acc2[ii][nt] = (f32x4){0.f,0.f,0.f,0.f};

  for (int it2 = 0; it2 < 18; ++it2){
    const int it = 18 + it2;
    const unsigned short* wb = &wbuf[it % 3][0];
    if (tid < 256 && it2 < 16){
      *reinterpret_cast<uint4*>(&wbuf[(it+2) % 3][wdst]) = wreg;  // slab it+2
      if (it2 < 15) wreg = *wsrc(it+3);                           // slab it+3
    }
    int tap = it2 >> 1, kf = it2 & 1;
    int icb = kf*32 + kg;
    bf16x8 Wf[4];
    #pragma unroll
    for (int nt = 0; nt < 4; ++nt)
      Wf[nt] = *reinterpret_cast<const bf16x8*>(wb + nt*512 + lrw);
    int t3 = tap/3;
    int dy = t3, dx = tap - t3*3;
    bf16x8 Pf[2];
    #pragma unroll
    for (int ii = 0; ii < 2; ++ii){
      int p = (wid*2 + ii + dy)*18 + lr + dx;
      Pf[ii] = *reinterpret_cast<const bf16x8*>(&xs[p*64 + (icb ^ ((p&7)*8))]);
    }
    #pragma unroll
    for (int ii = 0; ii < 2; ++ii)
      #pragma unroll
      for (int nt = 0; nt < 4; ++nt)
        acc2[ii][nt] = __builtin_amdgcn_mfma_f32_16x16x32_bf16(Wf[nt], Pf[ii], acc2[ii][nt], 0, 0, 0);
    asm volatile("s_waitcnt lgkmcnt(0)" ::: "memory");
    __builtin_amdgcn_s_barrier();
  }

  // ---- epilogue: bias + gate + resample + line-coalesced atomic accumulate
  // lane holds px = lr (16 consecutive), oc = nt*16 + l4 + j, conv row py = wid*2 + ii
  const size_t ob = (size_t)b*1048576;
  if (type == 0){
    #pragma unroll
    for (int ii = 0; ii < 2; ++ii){
      int gy = ty0 + wid*2 + ii;
      #pragma unroll
      for (int nt = 0; nt < 4; ++nt)
        #pragma unroll
        for (int j = 0; j < 4; ++j){
          int oc = nt*16 + l4 + j;
          atomicAdd(out + ob + (size_t)oc*16384 + gy*128 + tx0 + lr,
                    g*(acc2[ii][nt][j] + b2[e*64 + oc]));
        }
    }
  } else if (type == 1){
    // 2x2 maxpool: vertical pair in-register (ii 0/1), horizontal pair cross-lane
    int Py = (ty0 + wid*2) >> 1;
    int Px = (tx0 + lr) >> 1;
    #pragma unroll
    for (int nt = 0; nt < 4; ++nt)
      #pragma unroll
      for (int j = 0; j < 4; ++j){
        int oc = nt*16 + l4 + j;
        float v = fmaxf(acc2[0][nt][j], acc2[1][nt][j]);
        v = fmaxf(v, __shfl_xor(v, 1));
        if ((lane & 1) == 0)
          atomicAdd(out + ob + (size_t)oc*16384 + Py*128 + Px, g*(v + b2[e*64 + oc]));
      }
  } else {
    // nearest 2x upsample: each conv pixel -> 2x2 block at 128-res
    #pragma unroll
    for (int ii = 0; ii < 2; ++ii){
      int gy = (ty0 + wid*2 + ii)*2;
      #pragma unroll
      for (int nt = 0; nt < 4; ++nt)
        #pragma unroll
        for (int j = 0; j < 4; ++j){
          int oc = nt*16 + l4 + j;
          float v = g*(acc2[ii][nt][j] + b2[e*64 + oc]);
          float* o = out + ob + (size_t)oc*16384 + gy*128 + (tx0 + lr)*2;
          atomicAdd(o,       v); atomicAdd(o + 1,   v);
          atomicAdd(o + 128, v); atomicAdd(o + 129, v);
        }
    }
  }
}

extern "C" void kernel_launch(void* const* d_in, const int* in_sizes, int n_in,
                              void* d_out, int out_size, void* d_ws, size_t ws_size,
                              hipStream_t stream) {
  (void)in_sizes; (void)n_in; (void)ws_size;
  const float* x  = (const float*)d_in[0];
  const float* tf = (const float*)d_in[1];
  const float* Wx = (const float*)d_in[2];
  const float* Wt = (const float*)d_in[3];
  const float* bg = (const float*)d_in[4];
  const float* W1 = (const float*)d_in[5];
  const float* b1 = (const float*)d_in[6];
  const float* W2 = (const float*)d_in[7];
  const float* b2 = (const float*)d_in[8];
  float* out = (float*)d_out;
  unsigned short* wt = (unsigned short*)d_ws;
  float* wsf = (float*)d_ws;
  unsigned short* xtb = (unsigned short*)((char*)d_ws + XT_OFF_B);

  hipMemsetAsync(d_out, 0, (size_t)out_size*sizeof(float), stream);
  wtrans_kernel<<<4608, 256, 0, stream>>>(W1, W2, wt);
  xform_kernel<<<dim3(64, 16), 256, 0, stream>>>(x, xtb);
  pool_kernel<<<1024, 256, 0, stream>>>(x, wsf);
  gate_kernel<<<1, 256, 0, stream>>>(tf, Wx, Wt, bg, wsf, out + 16777216);

  moe_kernel<<<dim3(1744, 16), 512, 0, stream>>>(xtb, wt, wsf, b1, b2, out);
}

// Round 9
// 361.138 us; speedup vs baseline: 25.7672x; 1.1340x over previous
//
#include <hip/hip_runtime.h>
#include <cstdint>
#include <cstddef>

typedef __bf16 bf16x8 __attribute__((ext_vector_type(8)));
typedef float f32x4 __attribute__((ext_vector_type(4)));

// ---------------- ws layout ----------------
// bytes [0, 2359296): wt bf16 [16][2][9][64(oc)][64(ic)]
// float offset 589824: xp [16][64]; float offset 590848: gates [16][16]
// bytes [4MB, 4MB+33554432): xt bf16 [16][16384(pixel)][64(ch)]  (NHWC)
#define XP_OFF_F    589824
#define GATES_OFF_F 590848
#define XT_OFF_B    (4u<<20)

// LDS xs geometry: 8 chunks x 404 pixels x 8 ch (bf16). chunk stride 3232 ushorts.
#define XCH 3232

__device__ __forceinline__ float bf2f(unsigned short h){
  return __uint_as_float(((uint32_t)h)<<16);
}
__device__ __forceinline__ unsigned short f2bf(float f){
  uint32_t u = __float_as_uint(f);
  u = u + 0x7fffu + ((u>>16)&1u);   // RNE
  return (unsigned short)(u>>16);
}
// fast exact-GELU: erf via A&S 7.1.26 (|eps|<=1.5e-7, far below bf16 rounding)
__device__ __forceinline__ float gelu_exact(float x){
  float s = x * 0.70710678118654752440f;
  float a = __builtin_fabsf(s);
  float t = __builtin_amdgcn_rcpf(__builtin_fmaf(0.3275911f, a, 1.0f));
  float p = __builtin_fmaf(1.061405429f, t, -1.453152027f);
  p = __builtin_fmaf(p, t, 1.421413741f);
  p = __builtin_fmaf(p, t, -0.284496736f);
  p = __builtin_fmaf(p, t, 0.254829592f);
  p = p * t;
  float e = __expf(-a*a);
  float erfa = __builtin_fmaf(-p, e, 1.0f);
  float erfv = (s < 0.f) ? -erfa : erfa;
  return 0.5f * x * (1.0f + erfv);
}

// ---------------- weight transpose+cast: W[e][oc][ic][3][3] -> wt[e][c][tap][oc][ic] bf16
__global__ __launch_bounds__(256) void wtrans_kernel(const float* __restrict__ W1,
                                                     const float* __restrict__ W2,
                                                     unsigned short* __restrict__ wt){
  int idx = blockIdx.x*256 + threadIdx.x;      // 0 .. 1,179,647
  int ic  = idx & 63;
  int oc  = (idx>>6) & 63;
  int tap = (idx>>12) % 9;
  int ec  = idx / 36864;                       // e*2 + c
  int e = ec >> 1, c = ec & 1;
  const float* src = c ? W2 : W1;
  wt[idx] = f2bf(src[((e*64 + oc)*64 + ic)*9 + tap]);
}

// ---------------- x NCHW fp32 -> NHWC bf16
__global__ __launch_bounds__(256) void xform_kernel(const float* __restrict__ x,
                                                    unsigned short* __restrict__ xt){
  int b = blockIdx.y;
  int p = blockIdx.x*256 + threadIdx.x;        // 0..16383
  const float* xb = x + (size_t)b*1048576;
  unsigned short v[64];
  #pragma unroll
  for (int c = 0; c < 64; ++c)
    v[c] = f2bf(xb[c*16384 + p]);
  uint4* dst = reinterpret_cast<uint4*>(xt + (size_t)b*1048576 + (size_t)p*64);
  const uint4* src = reinterpret_cast<const uint4*>(v);
  #pragma unroll
  for (int i = 0; i < 8; ++i) dst[i] = src[i];
}

// ---------------- mean pool: xp[b][c] = mean_{h,w} x[b][c][h][w]
__global__ __launch_bounds__(256) void pool_kernel(const float* __restrict__ x,
                                                   float* __restrict__ wsf){
  int bc = blockIdx.x;                        // 0..1023
  const float* p = x + (size_t)bc*16384;
  int tid = threadIdx.x;
  float s = 0.f;
  for (int i = tid; i < 16384; i += 256) s += p[i];
  for (int off = 32; off; off >>= 1) s += __shfl_down(s, off);
  __shared__ float r[4];
  if ((tid & 63) == 0) r[tid>>6] = s;
  __syncthreads();
  if (tid == 0) wsf[XP_OFF_F + bc] = (r[0]+r[1]+r[2]+r[3]) * (1.0f/16384.0f);
}

// ---------------- gating: logits -> softmax -> top2 -> gates + aux
__global__ __launch_bounds__(256) void gate_kernel(const float* __restrict__ tf,
    const float* __restrict__ Wx, const float* __restrict__ Wt,
    const float* __restrict__ bg, float* __restrict__ wsf,
    float* __restrict__ out_aux){
  __shared__ float lg[16][16];
  __shared__ float gsh[16][16];
  int tid = threadIdx.x;
  int b = tid >> 4, e = tid & 15;
  const float* xp = wsf + XP_OFF_F;
  float acc = bg[e];
  for (int c = 0; c < 64;  ++c) acc += xp[b*64 + c] * Wx[c*16 + e];
  for (int d = 0; d < 512; ++d) acc += tf[b*512 + d] * Wt[d*16 + e];
  lg[b][e] = acc;
  __syncthreads();
  if (tid < 16) {
    int bb = tid;
    float m = -1e30f;
    for (int j = 0; j < 16; ++j) m = fmaxf(m, lg[bb][j]);
    float pr[16]; float s = 0.f;
    for (int j = 0; j < 16; ++j){ pr[j] = expf(lg[bb][j] - m); s += pr[j]; }
    float invs = 1.f/s;
    for (int j = 0; j < 16; ++j) pr[j] *= invs;
    int i1 = 0; float v1 = pr[0];
    for (int j = 1; j < 16; ++j) if (pr[j] > v1){ v1 = pr[j]; i1 = j; }
    float v2 = -1.f; int i2 = 0;
    for (int j = 0; j < 16; ++j) if (j != i1 && pr[j] > v2){ v2 = pr[j]; i2 = j; }
    float inv = 1.f/(v1 + v2);
    for (int j = 0; j < 16; ++j) gsh[bb][j] = 0.f;
    gsh[bb][i1] = v1*inv;
    gsh[bb][i2] = v2*inv;
    for (int j = 0; j < 16; ++j) wsf[GATES_OFF_F + bb*16 + j] = gsh[bb][j];
  }
  __syncthreads();
  if (tid == 0){
    float imp[16]; float mean = 0.f;
    for (int j = 0; j < 16; ++j){
      float t = 0.f;
      for (int bb = 0; bb < 16; ++bb) t += gsh[bb][j];
      imp[j] = t; mean += t;
    }
    mean *= (1.f/16.f);
    float m2 = 0.f;
    for (int j = 0; j < 16; ++j){ float d = imp[j] - mean; m2 += d*d; }
    float var = m2 * (1.f/16.f);
    out_aux[0] = var / (mean*mean + 1e-10f);
  }
}

// ---------------- merged MoE kernel: 512 threads, swapped-operand MFMA,
// chunked LDS layouts (no per-iter swizzle VALU), 8KB weight slabs, 3-deep pipeline.
// Per sample, blockIdx.x layout:
//   [0,384):     TYPE0, e = 3*(i/64),          tile = i%64   (8x8 tiles, S=128)
//   [384,1664):  TYPE1, e = 3*((i-384)/256)+1, tile = (i-384)%256 (16x16, S=256)
//   [1664,1744): TYPE2, e = 3*((i-1664)/16)+2, tile = (i-1664)%16 (4x4, S=64)
// conv as tap-decomposed GEMM: D[oc][px] = mfma(A=W[oc][ic], B=P[px][ic]).
__global__ __launch_bounds__(512, 4) void moe_kernel(
    const unsigned short* __restrict__ xt, const unsigned short* __restrict__ wt,
    const float* __restrict__ wsf,
    const float* __restrict__ b1, const float* __restrict__ b2,
    float* __restrict__ out)
{
  __shared__ unsigned short xs[8*XCH];     // 51.7 KB: [chunk][404 px][8 ch]; halo, then h1
  __shared__ unsigned short wbuf[3][4096]; // 24 KB: 3 x [64 oc][64 ic] tap slabs
  const int b = blockIdx.y;
  const int i = blockIdx.x;
  int e, tile, type, S, TILES;
  if (i < 384)       { type = 0; e = 3*(i>>6);            tile = i & 63;        S = 128; TILES = 8;  }
  else if (i < 1664) { type = 1; e = 3*((i-384)>>8) + 1;  tile = (i-384) & 255; S = 256; TILES = 16; }
  else               { type = 2; e = 3*((i-1664)>>4) + 2; tile = (i-1664) & 15; S = 64;  TILES = 4;  }

  const float g = wsf[GATES_OFF_F + b*16 + e];
  if (g == 0.0f) return;                 // inactive expert for this sample

  const int ty0 = (tile / TILES)*16;
  const int tx0 = (tile % TILES)*16;
  const int tid  = threadIdx.x;
  const int lane = tid & 63;
  const int wid  = tid >> 6;           // 0..7
  const int lr   = lane & 15;
  const int k16  = lane >> 4;          // 0..3
  const int l4   = k16 * 4;            // C/D row sub-offset

  const unsigned short* wt1 = wt + (size_t)(e*2 + 0)*36864;
  const unsigned short* wt2 = wt + (size_t)(e*2 + 1)*36864;
  const unsigned short* xtb = xt + (size_t)b*1048576;   // [pixel][64]

  // ---- weight staging: 512 threads x 16B per slab (slab j: j<9 -> wt1 tap j, else wt2 tap j-9)
  // LDS linear: thread t -> ushort t*8 (oc=t>>3, slot=t&7). Source chunk = slot ^ (oc&7).
  const int woc = tid >> 3, wch = tid & 7;
  const int wsc = wch ^ (woc & 7);
  auto wsrc = [&](int j)->const uint4*{
    const unsigned short* base = (j < 9) ? (wt1 + j*4096) : (wt2 + (j-9)*4096);
    return reinterpret_cast<const uint4*>(base + woc*64 + wsc*8);
  };
  // reader: Wf[nt](kf) = 16B at ushort (nt*16+lr)*64 + ((kf*4+k16)^(lr&7))*8
  const int wb0 = lr*64 + (((0*4+k16) ^ (lr&7))*8);   // kf=0 base (add nt*1024 as imm)
  const int wb1 = lr*64 + (((1*4+k16) ^ (lr&7))*8);   // kf=1 base

  // ---- stage 20x20x64 input halo -> xs[chunk][p][8]; 400 px, 1 per thread
  if (tid < 400){
    int p = tid;
    int hy = p/20, hx = p - hy*20;
    int sy = ty0 - 2 + hy, sx = tx0 - 2 + hx;      // conv-res coords
    bool valid = (sy >= 0) & (sy < S) & (sx < S) & (sx >= 0);
    if (!valid){
      uint4 z = make_uint4(0,0,0,0);
      #pragma unroll
      for (int c = 0; c < 8; ++c)
        *reinterpret_cast<uint4*>(&xs[c*XCH + p*8]) = z;
    } else if (type == 0){
      const uint4* src = reinterpret_cast<const uint4*>(xtb + ((size_t)(sy*128 + sx))*64);
      #pragma unroll
      for (int c = 0; c < 8; ++c)
        *reinterpret_cast<uint4*>(&xs[c*XCH + p*8]) = src[c];
    } else if (type == 1){
      const uint4* src = reinterpret_cast<const uint4*>(xtb + ((size_t)((sy>>1)*128 + (sx>>1)))*64);
      #pragma unroll
      for (int c = 0; c < 8; ++c)
        *reinterpret_cast<uint4*>(&xs[c*XCH + p*8]) = src[c];
    } else {
      // 2x2 maxpool on bf16 (exact: RNE is monotone)
      const uint4* q00 = reinterpret_cast<const uint4*>(xtb + ((size_t)(sy*256 + sx*2))*64);
      const uint4* q01 = q00 + 8;
      const uint4* q10 = q00 + 128*8;
      const uint4* q11 = q10 + 8;
      #pragma unroll
      for (int c = 0; c < 8; ++c){
        union { unsigned short u[8]; uint4 v; } a0,a1,a2,a3,o;
        a0.v = q00[c]; a1.v = q01[c]; a2.v = q10[c]; a3.v = q11[c];
        #pragma unroll
        for (int j = 0; j < 8; ++j){
          float m = fmaxf(fmaxf(bf2f(a0.u[j]), bf2f(a1.u[j])),
                          fmaxf(bf2f(a2.u[j]), bf2f(a3.u[j])));
          o.u[j] = f2bf(m);
        }
        *reinterpret_cast<uint4*>(&xs[c*XCH + p*8]) = o.v;
      }
    }
  }

  // ---- weight pipeline prologue: slabs 0,1 -> LDS; slab 2 -> regs
  uint4 wreg;
  {
    uint4 w0 = *wsrc(0);
    uint4 w1 = *wsrc(1);
    *reinterpret_cast<uint4*>(&wbuf[0][tid*8]) = w0;
    *reinterpret_cast<uint4*>(&wbuf[1][tid*8]) = w1;
    wreg = *wsrc(2);
  }

  // conv1 B-frag pixel bases (halo coords): 24 frags of 16 over 324 h1 px (clamped)
  int pb1[3];
  #pragma unroll
  for (int ii = 0; ii < 3; ++ii){
    int q = (wid*3 + ii)*16 + lr;
    q = q > 323 ? 323 : q;
    pb1[ii] = ((q/18)*20 + (q%18))*8 + k16*XCH;    // ushort base; +kf*4*XCH, +poff*8 as imm
  }

  asm volatile("s_waitcnt lgkmcnt(0)" ::: "memory");
  __builtin_amdgcn_s_barrier();

  // ---- conv1: 9 fully-unrolled taps; per tap: stage next slab, 14 ds_read, 24 MFMA
  f32x4 acc1[3][4];
  #pragma unroll
  for (int ii = 0; ii < 3; ++ii)
    #pragma unroll
    for (int nt = 0; nt < 4; ++nt)
      acc1[ii][nt] = (f32x4){0.f,0.f,0.f,0.f};

  #pragma unroll
  for (int t = 0; t < 9; ++t){
    const unsigned short* wb = &wbuf[t % 3][0];
    *reinterpret_cast<uint4*>(&wbuf[(t+2) % 3][tid*8]) = wreg;   // slab t+2
    wreg = *wsrc(t+3);                                           // slab t+3
    const int poff = ((t/3)*20 + (t%3))*8;
    #pragma unroll
    for (int kf = 0; kf < 2; ++kf){
      bf16x8 Wf[4];
      #pragma unroll
      for (int nt = 0; nt < 4; ++nt)
        Wf[nt] = *reinterpret_cast<const bf16x8*>(wb + (kf ? wb1 : wb0) + nt*1024);
      bf16x8 Pf[3];
      #pragma unroll
      for (int ii = 0; ii < 3; ++ii)
        Pf[ii] = *reinterpret_cast<const bf16x8*>(&xs[pb1[ii] + kf*4*XCH + poff]);
      #pragma unroll
      for (int ii = 0; ii < 3; ++ii)
        #pragma unroll
        for (int nt = 0; nt < 4; ++nt)
          acc1[ii][nt] = __builtin_amdgcn_mfma_f32_16x16x32_bf16(Wf[nt], Pf[ii], acc1[ii][nt], 0, 0, 0);
    }
    asm volatile("s_waitcnt lgkmcnt(0)" ::: "memory");
    __builtin_amdgcn_s_barrier();
  }

  // ---- bias + GELU -> h1 in xs[chunk][q][8] (zero outside image: ref zero-pads h1)
  #pragma unroll
  for (int ii = 0; ii < 3; ++ii){
    int q = (wid*3 + ii)*16 + lr;
    if (q < 324){
      int qy = q/18, qx = q - qy*18;
      int gy = ty0 - 1 + qy, gx = tx0 - 1 + qx;
      bool in_img = (gy >= 0) & (gy < S) & (gx >= 0) & (gx < S);
      int hb = (l4 >> 3)*XCH + q*8 + (l4 & 4);     // + nt*2*XCH as imm
      #pragma unroll
      for (int nt = 0; nt < 4; ++nt){
        unsigned short v4[4];
        #pragma unroll
        for (int j = 0; j < 4; ++j){
          int oc = nt*16 + l4 + j;
          float v = in_img ? gelu_exact(acc1[ii][nt][j] + b1[e*64 + oc]) : 0.f;
          v4[j] = f2bf(v);
        }
        *reinterpret_cast<uint2*>(&xs[nt*2*XCH + hb]) = *reinterpret_cast<uint2*>(v4);
      }
    }
  }

  asm volatile("s_waitcnt lgkmcnt(0)" ::: "memory");
  __builtin_amdgcn_s_barrier();

  // conv2 B-frag pixel bases
  int pb2[2];
  #pragma unroll
  for (int ii = 0; ii < 2; ++ii)
    pb2[ii] = ((wid*2 + ii)*18 + lr)*8 + k16*XCH;

  // ---- conv2: 9 fully-unrolled taps (slabs 9..17)
  f32x4 acc2[2][4];
  #pragma unroll
  for (int ii = 0; ii < 2; ++ii)
    #pragma unroll
    for (int nt = 0; nt < 4; ++nt)
      acc2[ii][nt] = (f32x4){0.f,0.f,0.f,0.f};

  #pragma unroll
  for (int t2 = 0; t2 < 9; ++t2){
    const int t = 9 + t2;
    const unsigned short* wb = &wbuf[t % 3][0];
    if (t2 < 7){
      *reinterpret_cast<uint4*>(&wbuf[(t+2) % 3][tid*8]) = wreg;  // slab t+2
      if (t2 < 6) wreg = *wsrc(t+3);                              // slab t+3
    }
    const int poff = ((t2/3)*18 + (t2%3))*8;
    #pragma unroll
    for (int kf = 0; kf < 2; ++kf){
      bf16x8 Wf[4];
      #pragma unroll
      for (int nt = 0; nt < 4; ++nt)
        Wf[nt] = *reinterpret_cast<const bf16x8*>(wb + (kf ? wb1 : wb0) + nt*1024);
      bf16x8 Pf[2];
      #pragma unroll
      for (int ii = 0; ii < 2; ++ii)
        Pf[ii] = *reinterpret_cast<const bf16x8*>(&xs[pb2[ii] + kf*4*XCH + poff]);
      #pragma unroll
      for (int ii = 0; ii < 2; ++ii)
        #pragma unroll
        for (int nt = 0; nt < 4; ++nt)
          acc2[ii][nt] = __builtin_amdgcn_mfma_f32_16x16x32_bf16(Wf[nt], Pf[ii], acc2[ii][nt], 0, 0, 0);
    }
    asm volatile("s_waitcnt lgkmcnt(0)" ::: "memory");
    __builtin_amdgcn_s_barrier();
  }

  // ---- epilogue: bias + gate + resample + line-coalesced atomic accumulate
  // lane holds px = lr (16 consecutive), oc = nt*16 + l4 + j, conv row py = wid*2 + ii
  const size_t ob = (size_t)b*1048576;
  if (type == 0){
    #pragma unroll
    for (int ii = 0; ii < 2; ++ii){
      int gy = ty0 + wid*2 + ii;
      #pragma unroll
      for (int nt = 0; nt < 4; ++nt)
        #pragma unroll
        for (int j = 0; j < 4; ++j){
          int oc = nt*16 + l4 + j;
          atomicAdd(out + ob + (size_t)oc*16384 + gy*128 + tx0 + lr,
                    g*(acc2[ii][nt][j] + b2[e*64 + oc]));
        }
    }
  } else if (type == 1){
    // 2x2 maxpool: vertical pair in-register (ii 0/1), horizontal pair cross-lane
    int Py = (ty0 + wid*2) >> 1;
    int Px = (tx0 + lr) >> 1;
    #pragma unroll
    for (int nt = 0; nt < 4; ++nt)
      #pragma unroll
      for (int j = 0; j < 4; ++j){
        int oc = nt*16 + l4 + j;
        float v = fmaxf(acc2[0][nt][j], acc2[1][nt][j]);
        v = fmaxf(v, __shfl_xor(v, 1));
        if ((lane & 1) == 0)
          atomicAdd(out + ob + (size_t)oc*16384 + Py*128 + Px, g*(v + b2[e*64 + oc]));
      }
  } else {
    // nearest 2x upsample: each conv pixel -> 2x2 block at 128-res
    #pragma unroll
    for (int ii = 0; ii < 2; ++ii){
      int gy = (ty0 + wid*2 + ii)*2;
      #pragma unroll
      for (int nt = 0; nt < 4; ++nt)
        #pragma unroll
        for (int j = 0; j < 4; ++j){
          int oc = nt*16 + l4 + j;
          float v = g*(acc2[ii][nt][j] + b2[e*64 + oc]);
          float* o = out + ob + (size_t)oc*16384 + gy*128 + (tx0 + lr)*2;
          atomicAdd(o,       v); atomicAdd(o + 1,   v);
          atomicAdd(o + 128, v); atomicAdd(o + 129, v);
        }
    }
  }
}

extern "C" void kernel_launch(void* const* d_in, const int* in_sizes, int n_in,
                              void* d_out, int out_size, void* d_ws, size_t ws_size,
                              hipStream_t stream) {
  (void)in_sizes; (void)n_in; (void)ws_size;
  const float* x  = (const float*)d_in[0];
  const float* tf = (const float*)d_in[1];
  const float* Wx = (const float*)d_in[2];
  const float* Wt = (const float*)d_in[3];
  const float* bg = (const float*)d_in[4];
  const float* W1 = (const float*)d_in[5];
  const float* b1 = (const float*)d_in[6];
  const float* W2 = (const float*)d_in[7];
  const float* b2 = (const float*)d_in[8];
  float* out = (float*)d_out;
  unsigned short* wt = (unsigned short*)d_ws;
  float* wsf = (float*)d_ws;
  unsigned short* xtb = (unsigned short*)((char*)d_ws + XT_OFF_B);

  hipMemsetAsync(d_out, 0, (size_t)out_size*sizeof(float), stream);
  wtrans_kernel<<<4608, 256, 0, stream>>>(W1, W2, wt);
  xform_kernel<<<dim3(64, 16), 256, 0, stream>>>(x, xtb);
  pool_kernel<<<1024, 256, 0, stream>>>(x, wsf);
  gate_kernel<<<1, 256, 0, stream>>>(tf, Wx, Wt, bg, wsf, out + 16777216);

  moe_kernel<<<dim3(1744, 16), 512, 0, stream>>>(xtb, wt, wsf, b1, b2, out);
}